// Round 10
// baseline (686.441 us; speedup 1.0000x reference)
//
#include <hip/hip_runtime.h>

// Loihi SNN, 3 layers of (GEMM -> Loihi scan -> delay).
// Round 10: faithful m201 8-phase GEMM template port.
//   BM=BN=256, BK=64, 8 waves (2Mx4N), wave output 128x64.
//   LDS 128KB = 8 planes [dbuf2][op2][ks2] of 256x32 bf16 (16KB each);
//   each plane uses the r7/r9-proven zero-conflict swizzle key (row>>1)&3.
//   8 phases per iter (2 K-tiles): {ds_read (4 or 8) || stage 1 unit
//   (2 gload_lds) -> barrier -> lgkmcnt(0) -> setprio(1) -> 16 MFMA ->
//   setprio(0) -> barrier}; vmcnt(6) ONLY at phases 4/8 (unit needed next
//   is always >=3 units = 6 loads old); vmcnt(0) only in last iteration.
//   Stage schedule (t=2i):  ph1:A1(t+1) ph2:B0(t+2) ph3:A0(t+2) ph4:B1(t+2)
//                           ph5:A1(t+2) ph6:B0(t+3) ph7:A0(t+3) ph8:B1(t+3)
//   every target plane is freed (last ds_read) >=1 barrier earlier.
//
// W-planes stacked along M (single A stream): W2 = [W_hi; W_mid], M2=2C.
// Scans sum plane pairs (X[c] + X[c+C]) and K-split partials in fixed order.

typedef unsigned short u16;
typedef unsigned int u32;
typedef __attribute__((ext_vector_type(8))) short short8;
typedef __attribute__((ext_vector_type(4))) float f32x4;

#define GLOAD16(g, l)                                                         \
    __builtin_amdgcn_global_load_lds(                                         \
        (const __attribute__((address_space(1))) u32*)(g),                    \
        (__attribute__((address_space(3))) u32*)(l), 16, 0, 0)

__device__ __forceinline__ u16 f2bf_trunc(float x) {
    return (u16)(__float_as_uint(x) >> 16);
}

// ---------------- W -> stacked 2-plane RNE split ----------------
__global__ void split_w2s(const float* __restrict__ W, u16* __restrict__ W2,
                          int C, int K, int KLD)
{
    const int c = blockIdx.y;
    const int k = blockIdx.x * 256 + threadIdx.x;
    if (k >= KLD) return;
    float w = (k < K) ? W[(size_t)c * K + k] : 0.f;
    u32 b  = __float_as_uint(w);
    u32 hb = (b + 0x7FFFu + ((b >> 16) & 1u)) & 0xFFFF0000u;
    float r = w - __uint_as_float(hb);
    u32 rb = __float_as_uint(r);
    u32 mb = (rb + 0x7FFFu + ((rb >> 16) & 1u)) & 0xFFFF0000u;
    W2[(size_t)c * KLD + k]       = (u16)(hb >> 16);
    W2[((size_t)C + c) * KLD + k] = (u16)(mb >> 16);
}

// ------- spikes fp32 [n][I][400] -> bf16 [n*400+t][KLD] (transpose) -------
__global__ __launch_bounds__(256) void cvt_sp(const float* __restrict__ S,
                                              u16* __restrict__ Sp,
                                              int I, int KLD)
{
    __shared__ u16 tile[64][80];
    const int n  = blockIdx.z;
    const int i0 = blockIdx.y * 64;
    const int t0 = blockIdx.x * 64;
    const int tid = threadIdx.x;

    const int il = tid >> 2;
    const int q  = tid & 3;
    const int gi = i0 + il;
    const bool iok = gi < I;
    const float* srow = S + ((size_t)n * I + gi) * 400 + t0;

    #pragma unroll
    for (int s = 0; s < 4; ++s) {
        const int fi = s * 4 + q;
        const int tl = fi * 4;
        float4 v = make_float4(0.f, 0.f, 0.f, 0.f);
        if (iok && (t0 + tl) < 400)
            v = *(const float4*)(srow + tl);
        tile[tl + 0][il] = f2bf_trunc(v.x);
        tile[tl + 1][il] = f2bf_trunc(v.y);
        tile[tl + 2][il] = f2bf_trunc(v.z);
        tile[tl + 3][il] = f2bf_trunc(v.w);
    }
    __syncthreads();

    const int tl = tid >> 2;
    const int iq = tid & 3;
    const int t  = t0 + tl;
    const int go = i0 + iq * 16;
    if (t < 400 && go < KLD) {
        u16* dst = Sp + (size_t)(n * 400 + t) * KLD + go;
        *(short8*)(dst)     = *(const short8*)&tile[tl][iq * 16];
        *(short8*)(dst + 8) = *(const short8*)&tile[tl][iq * 16 + 8];
    }
}

// ---------------- 8-phase deep-pipelined bf16 MFMA GEMM ----------------
// X[z][nt][c] = sum_{k in chunk z} A[c][k] * B[nt][k]
__global__ __launch_bounds__(512, 2) void gemm8(
    const u16* __restrict__ A,   // [M2][KLD]
    const u16* __restrict__ B,   // [12800][KLD]
    float* __restrict__ Xbase,   // [z][12800][M2]
    int M2, int KLD, int ktPerZ, int ktTotal)
{
    __shared__ u16 lds[65536];   // 128 KB: [d2][op2][ks2] planes of 256x32

    // bijective XCD-aware block swizzle (all launches have nwg % 8 == 0)
    const int Dx = gridDim.x, Dy = gridDim.y;
    int f = blockIdx.x + Dx * (blockIdx.y + Dy * blockIdx.z);
    const int nwg = Dx * Dy * gridDim.z;
    f = (f & 7) * (nwg >> 3) + (f >> 3);
    const int bx = f % Dx;
    const int by = (f / Dx) % Dy;
    const int bz = f / (Dx * Dy);

    const int c0  = bx * 256;
    const int nt0 = by * 256;
    const int kt0 = bz * ktPerZ;
    const int nk  = min(ktTotal - kt0, ktPerZ);   // always even here
    float* __restrict__ X = Xbase + (size_t)bz * 12800 * M2;

    const int tid  = threadIdx.x;
    const int lane = tid & 63, w = tid >> 6;
    const int wm = w >> 2, wn = w & 3;
    const int l15 = lane & 15, l16 = lane >> 4;

    // frag-read addressing within a plane (zero-conflict key (row>>1)&3)
    const int swzg  = (l16 ^ ((l15 >> 1) & 3)) * 8;
    const int aBase = (wm * 128 + l15) * 32 + swzg;          // + mf*512
    const int bBase = 16384 + (wn * 64 + l15) * 32 + swzg;   // + nf*512
    // plane offset: d*32768 + ks*8192 (A); B adds 16384.

    // staging: LDS granule (row=tid>>2, g=tid&3) <- global granule g^((tid>>3)&3)
    const int gsw = ((tid & 3) ^ ((tid >> 3) & 3)) * 8;
    const u16* pA = A + (size_t)(c0 + (tid >> 2)) * KLD + gsw;
    const u16* pB = B + (size_t)(nt0 + (tid >> 2)) * KLD + gsw;
    u16* const ldsW = &lds[w * 512];

#define STG(op, d, ks, tt) do {                                               \
    const u16* s_ = ((op) ? pB : pA) + (size_t)(tt) * 64 + (ks) * 32;         \
    GLOAD16(s_, ldsW + (d) * 32768 + (op) * 16384 + (ks) * 8192);             \
    GLOAD16(s_ + (size_t)128 * KLD,                                           \
            ldsW + (d) * 32768 + (op) * 16384 + (ks) * 8192 + 4096);          \
} while (0)

#define PH(d, ks, mh, LOADB, STAGE_STMT, WAIT_STMT) do {                      \
    short8 a_[4];                                                             \
    _Pragma("unroll")                                                         \
    for (int mf = 0; mf < 4; ++mf)                                            \
        a_[mf] = *(const short8*)&lds[(d) * 32768 + (ks) * 8192 + aBase       \
                                      + ((mh) * 4 + mf) * 512];               \
    if (LOADB) {                                                              \
        _Pragma("unroll")                                                     \
        for (int nf = 0; nf < 4; ++nf)                                        \
            bcur[nf] = *(const short8*)&lds[(d) * 32768 + (ks) * 8192 + bBase \
                                            + nf * 512];                      \
    }                                                                         \
    STAGE_STMT;                                                               \
    __builtin_amdgcn_s_barrier();                                             \
    asm volatile("s_waitcnt lgkmcnt(0)" ::: "memory");                        \
    __builtin_amdgcn_sched_barrier(0);                                        \
    __builtin_amdgcn_s_setprio(1);                                            \
    _Pragma("unroll")                                                         \
    for (int mf = 0; mf < 4; ++mf)                                            \
        _Pragma("unroll")                                                     \
        for (int nf = 0; nf < 4; ++nf)                                        \
            acc[(mh) * 4 + mf][nf] = __builtin_amdgcn_mfma_f32_16x16x32_bf16( \
                a_[mf], bcur[nf], acc[(mh) * 4 + mf][nf], 0, 0, 0);           \
    __builtin_amdgcn_s_setprio(0);                                            \
    WAIT_STMT;                                                                \
    __builtin_amdgcn_s_barrier();                                             \
    asm volatile("" ::: "memory");                                            \
} while (0)

    f32x4 acc[8][4];
    #pragma unroll
    for (int i = 0; i < 8; ++i)
        #pragma unroll
        for (int j = 0; j < 4; ++j)
            acc[i][j] = (f32x4){0.f, 0.f, 0.f, 0.f};

    // prologue: tile0 all 4 units (d0), tile1 A-ks0/B-ks0/B-ks1 (d1);
    // A-ks1(tile1) is staged by iter-0 phase 1.
    STG(0, 0, 0, kt0); STG(1, 0, 0, kt0); STG(0, 0, 1, kt0); STG(1, 0, 1, kt0);
    if (nk > 1) { STG(0, 1, 0, kt0 + 1); STG(1, 1, 0, kt0 + 1); STG(1, 1, 1, kt0 + 1); }
    asm volatile("s_waitcnt vmcnt(0)" ::: "memory");
    __builtin_amdgcn_s_barrier();
    asm volatile("" ::: "memory");

    const int I = nk >> 1;
    for (int i = 0; i < I; ++i) {
        const int t = kt0 + 2 * i;
        const bool pf = (i < I - 1);
        short8 bcur[4];
        // tile t (dbuf 0)
        PH(0, 0, 0, 1, { STG(0, 1, 1, t + 1); }, );
        PH(0, 0, 1, 0, { if (pf) STG(1, 0, 0, t + 2); }, );
        PH(0, 1, 0, 1, { if (pf) STG(0, 0, 0, t + 2); }, );
        PH(0, 1, 1, 0, { if (pf) STG(1, 0, 1, t + 2); },
           { if (pf) asm volatile("s_waitcnt vmcnt(6)" ::: "memory");
             else    asm volatile("s_waitcnt vmcnt(0)" ::: "memory"); });
        // tile t+1 (dbuf 1)
        PH(1, 0, 0, 1, { if (pf) STG(0, 0, 1, t + 2); }, );
        PH(1, 0, 1, 0, { if (pf) STG(1, 1, 0, t + 3); }, );
        PH(1, 1, 0, 1, { if (pf) STG(0, 1, 0, t + 3); }, );
        PH(1, 1, 1, 0, { if (pf) STG(1, 1, 1, t + 3); },
           { if (pf) asm volatile("s_waitcnt vmcnt(6)" ::: "memory");
             else    asm volatile("s_waitcnt vmcnt(0)" ::: "memory"); });
    }

    // epilogue: D col=lane&15 -> nt, row=(lane>>4)*4+reg -> c (m89-verified)
    #pragma unroll
    for (int mf = 0; mf < 8; ++mf) {
        const int c = c0 + wm * 128 + mf * 16 + l16 * 4;
        #pragma unroll
        for (int nf = 0; nf < 4; ++nf) {
            const int nt = nt0 + wn * 64 + nf * 16 + l15;
            *(f32x4*)&X[(size_t)nt * M2 + c] = acc[mf][nf];
        }
    }
#undef STG
#undef PH
}

// ---------------- Loihi scans (16-deep pipelined loads, 64-thr blocks) -----
__device__ __forceinline__ float loihi_step(float xt, float& u, float& v)
{
    u = truncf(u * 0.75f) + 64.f * xt;
    v = truncf(v * 0.96875f) + u;
    if (v >= 5120.f) { v = 0.f; return 1.f; }
    return 0.f;
}

// scan_ab: tact (stacked pair) + vis (2 partials, stacked pairs) -> Sc bf16
__global__ __launch_bounds__(64) void scan_ab(const float* __restrict__ Xt,
                                              const float* __restrict__ Xv,
                                              u16* __restrict__ Sc)
{
    const int gid = blockIdx.x * 64 + threadIdx.x;   // 32*1024 threads
    const int n = gid >> 10;
    const int c = gid & 1023;
    const size_t PS = (size_t)12800 * 1024;          // vis partial stride

    u16* srow = Sc + (size_t)(n * 400) * 1024 + c;
    srow[0] = 0;

    float buf[16];
    float u = 0.f, v = 0.f;

    if (c < 512) {
        const float* xr = Xt + (size_t)(n * 400) * 1024 + c;
        #pragma unroll
        for (int d = 0; d < 16; ++d) {
            const size_t o = (size_t)d * 1024;
            buf[d] = xr[o] + xr[o + 512];
        }
        #pragma unroll 16
        for (int t = 0; t < 400; ++t) {
            const float xt = buf[t & 15];
            const int tn = t + 16;
            float nx = 0.f;
            if (tn < 400) {
                const size_t o = (size_t)tn * 1024;
                nx = xr[o] + xr[o + 512];
            }
            buf[t & 15] = nx;
            const float sp = loihi_step(xt, u, v);
            if (t < 399) srow[(size_t)(t + 1) * 1024] = (sp != 0.f) ? (u16)0x3F80 : (u16)0;
        }
    } else {
        const float* xr = Xv + (size_t)(n * 400) * 1024 + (c - 512);
        #pragma unroll
        for (int d = 0; d < 16; ++d) {
            const size_t o = (size_t)d * 1024;
            buf[d] = (xr[o] + xr[o + 512]) + (xr[o + PS] + xr[o + PS + 512]);
        }
        #pragma unroll 16
        for (int t = 0; t < 400; ++t) {
            const float xt = buf[t & 15];
            const int tn = t + 16;
            float nx = 0.f;
            if (tn < 400) {
                const size_t o = (size_t)tn * 1024;
                nx = (xr[o] + xr[o + 512]) + (xr[o + PS] + xr[o + PS + 512]);
            }
            buf[t & 15] = nx;
            const float sp = loihi_step(xt, u, v);
            if (t < 399) srow[(size_t)(t + 1) * 1024] = (sp != 0.f) ? (u16)0x3F80 : (u16)0;
        }
    }
}

// scan_c: combi (2 partials, stacked pairs at +256) -> out [n][c][t]
__global__ __launch_bounds__(64) void scan_c(const float* __restrict__ Xc,
                                             float* __restrict__ out)
{
    const int gid = blockIdx.x * 64 + threadIdx.x;   // 32*256 threads
    const int n = gid >> 8;
    const int c = gid & 255;
    const size_t PS = (size_t)12800 * 512;
    const float* xr = Xc + (size_t)(n * 400) * 512 + c;
    float* orow = out + ((size_t)n * 256 + c) * 400;
    orow[0] = 0.f;

    float buf[16];
    #pragma unroll
    for (int d = 0; d < 16; ++d) {
        const size_t o = (size_t)d * 512;
        buf[d] = (xr[o] + xr[o + 256]) + (xr[o + PS] + xr[o + PS + 256]);
    }
    float u = 0.f, v = 0.f;
    #pragma unroll 16
    for (int t = 0; t < 400; ++t) {
        const float xt = buf[t & 15];
        const int tn = t + 16;
        float nx = 0.f;
        if (tn < 400) {
            const size_t o = (size_t)tn * 512;
            nx = (xr[o] + xr[o + 256]) + (xr[o + PS] + xr[o + PS + 256]);
        }
        buf[t & 15] = nx;
        const float sp = loihi_step(xt, u, v);
        if (t < 399) orow[t + 1] = sp;
    }
}

extern "C" void kernel_launch(void* const* d_in, const int* in_sizes, int n_in,
                              void* d_out, int out_size, void* d_ws, size_t ws_size,
                              hipStream_t stream)
{
    const float* tact   = (const float*)d_in[0];  // [32][156][400]
    const float* vis    = (const float*)d_in[1];  // [32][6300][400]
    const float* W_tact = (const float*)d_in[2];  // [512][156]
    const float* W_vis  = (const float*)d_in[3];  // [512][6300]
    const float* W_comb = (const float*)d_in[4];  // [256][1024]
    float* out = (float*)d_out;                   // [32][256][400]

    const int NT = 32 * 400;            // 12800
    const int Ktp = 256;                // tact K pad: 4 K-tiles of 64 (even)
    const int Kvp = 6400;               // vis K pad: 100 K-tiles (even halves)
    const int Kc  = 1024;               // combi K: 16 K-tiles

    // ---- workspace carve-up: 289.9 MB (round-3 proved >=291 MB available) --
    char* p = (char*)d_ws;
    u16* Sv  = (u16*)p;                p += (size_t)NT * Kvp * 2;        // 163.8MB
    u16* St  = (u16*)p;                p += (size_t)NT * Ktp * 2;        //   6.6MB
    u16* Wt2 = (u16*)p;                p += (size_t)1024 * Ktp * 2;      //   0.5MB
    u16* Wv2 = (u16*)p;                p += (size_t)1024 * Kvp * 2;      //  13.1MB
    u16* Wc2 = (u16*)p;                p += (size_t)512 * Kc * 2;        //   1.0MB
    float* Xv = (float*)p;             p += (size_t)2 * NT * 1024 * 4;   // 104.9MB
    // aliases into Sv region (Sv dead after vis gemm; tact gemm runs after):
    float* Xt = (float*)Sv;                                        // [NT][1024] f32
    u16*   Sc = (u16*)((char*)Sv + (size_t)NT * 1024 * 4);         // [NT][1024] bf16
    float* Xc = (float*)((char*)Sv + (size_t)NT * 1024 * 4 + (size_t)NT * 1024 * 2); // [2][NT][512]

    // 1) weight splits (stacked 2 RNE planes)
    split_w2s<<<dim3(Kvp / 256, 512), 256, 0, stream>>>(W_vis,  Wv2, 512, 6300, Kvp);
    split_w2s<<<dim3(Ktp / 256, 512), 256, 0, stream>>>(W_tact, Wt2, 512, 156,  Ktp);
    split_w2s<<<dim3(Kc  / 256, 256), 256, 0, stream>>>(W_comb, Wc2, 256, 1024, Kc);

    // 2) spike transpose+convert
    cvt_sp<<<dim3(7, Kvp / 64, 32), 256, 0, stream>>>(vis,  Sv, 6300, Kvp);
    cvt_sp<<<dim3(7, Ktp / 64, 32), 256, 0, stream>>>(tact, St, 156,  Ktp);

    // 3) vis GEMM first (reads Sv), THEN tact GEMM (writes Xt over dead Sv)
    gemm8<<<dim3(1024 / 256, NT / 256, 2), 512, 0, stream>>>(Wv2, Sv, Xv, 1024, Kvp, 50, 100);
    gemm8<<<dim3(1024 / 256, NT / 256, 1), 512, 0, stream>>>(Wt2, St, Xt, 1024, Ktp, 4, 4);

    // 4) scan layers 1+2 -> combi spikes (bf16, [nt][1024])
    scan_ab<<<dim3((32 * 1024) / 64), 64, 0, stream>>>(Xt, Xv, Sc);

    // 5) combi GEMM (z=2 K-chunks of 8 tiles) + scan -> out
    gemm8<<<dim3(512 / 256, NT / 256, 2), 512, 0, stream>>>(Wc2, Sc, Xc, 512, Kc, 8, 16);
    scan_c<<<dim3((32 * 256) / 64), 64, 0, stream>>>(Xc, out);

    (void)in_sizes; (void)n_in; (void)out_size; (void)ws_size;
}

// Round 11
// 595.757 us; speedup vs baseline: 1.1522x; 1.1522x over previous
//
#include <hip/hip_runtime.h>

// Loihi SNN, 3 layers of (GEMM -> Loihi scan -> delay).
// Round 11:
//  - Panel co-location XCD map for the vis GEMM: the 4 blocks sharing a
//    B-panel (same by,bz) land on one XCD-pair within ~9 dispatch slots ->
//    B streams through 2 L2s instead of 4, A-chunk becomes L2-resident.
//    (Previous swizzle spread mates across 4 XCDs -> ~6.5 TB/s L3 demand.)
//  - W2 planes interleaved at 16-row granularity: [hi0 mid0 hi1 mid1 ...] ->
//    acc[2j] + acc[2j+1] fold IN-REGISTER in the epilogue; X halves
//    (-105 MB write, -79 MB scan read).
//  - tact GEMM fused into the vis launch (bz=2); Xt de-aliased from Sv.
//  - GEMM core: unchanged r10 8-phase template (faithful m201 port).

typedef unsigned short u16;
typedef unsigned int u32;
typedef __attribute__((ext_vector_type(8))) short short8;
typedef __attribute__((ext_vector_type(4))) float f32x4;

#define GLOAD16(g, l)                                                         \
    __builtin_amdgcn_global_load_lds(                                         \
        (const __attribute__((address_space(1))) u32*)(g),                    \
        (__attribute__((address_space(3))) u32*)(l), 16, 0, 0)

__device__ __forceinline__ u16 f2bf_trunc(float x) {
    return (u16)(__float_as_uint(x) >> 16);
}

// ------- W -> 2 RNE bf16 planes, interleaved 16-row groups -------
// channel c -> rows: hi at ((c>>4)<<5)|(c&15), mid at +16.  M2 = 2C rows.
__global__ void split_w2s(const float* __restrict__ W, u16* __restrict__ W2,
                          int C, int K, int KLD)
{
    const int c = blockIdx.y;
    const int k = blockIdx.x * 256 + threadIdx.x;
    if (k >= KLD) return;
    float w = (k < K) ? W[(size_t)c * K + k] : 0.f;
    u32 b  = __float_as_uint(w);
    u32 hb = (b + 0x7FFFu + ((b >> 16) & 1u)) & 0xFFFF0000u;
    float r = w - __uint_as_float(hb);
    u32 rb = __float_as_uint(r);
    u32 mb = (rb + 0x7FFFu + ((rb >> 16) & 1u)) & 0xFFFF0000u;
    const int rh = ((c >> 4) << 5) | (c & 15);
    W2[(size_t)rh * KLD + k]        = (u16)(hb >> 16);
    W2[(size_t)(rh + 16) * KLD + k] = (u16)(mb >> 16);
}

// ------- spikes fp32 [n][I][400] -> bf16 [n*400+t][KLD] (transpose) -------
__global__ __launch_bounds__(256) void cvt_sp(const float* __restrict__ S,
                                              u16* __restrict__ Sp,
                                              int I, int KLD)
{
    __shared__ u16 tile[64][80];
    const int n  = blockIdx.z;
    const int i0 = blockIdx.y * 64;
    const int t0 = blockIdx.x * 64;
    const int tid = threadIdx.x;

    const int il = tid >> 2;
    const int q  = tid & 3;
    const int gi = i0 + il;
    const bool iok = gi < I;
    const float* srow = S + ((size_t)n * I + gi) * 400 + t0;

    #pragma unroll
    for (int s = 0; s < 4; ++s) {
        const int fi = s * 4 + q;
        const int tl = fi * 4;
        float4 v = make_float4(0.f, 0.f, 0.f, 0.f);
        if (iok && (t0 + tl) < 400)
            v = *(const float4*)(srow + tl);
        tile[tl + 0][il] = f2bf_trunc(v.x);
        tile[tl + 1][il] = f2bf_trunc(v.y);
        tile[tl + 2][il] = f2bf_trunc(v.z);
        tile[tl + 3][il] = f2bf_trunc(v.w);
    }
    __syncthreads();

    const int tl = tid >> 2;
    const int iq = tid & 3;
    const int t  = t0 + tl;
    const int go = i0 + iq * 16;
    if (t < 400 && go < KLD) {
        u16* dst = Sp + (size_t)(n * 400 + t) * KLD + go;
        *(short8*)(dst)     = *(const short8*)&tile[tl][iq * 16];
        *(short8*)(dst + 8) = *(const short8*)&tile[tl][iq * 16 + 8];
    }
}

// ---------------- 8-phase GEMM core (r10 template, fold-epilogue) ----------
// X[nt][cg] = sum_k (hi+mid planes folded) ; A rows interleaved 16-gran.
__device__ __forceinline__ void gemm_core(
    const u16* __restrict__ A, const u16* __restrict__ B,
    float* __restrict__ X, int M2, int KLD, int kt0, int nk,
    int bx, int by, u16* lds)
{
    const int c0  = bx * 256;
    const int nt0 = by * 256;
    const int tid  = threadIdx.x;
    const int lane = tid & 63, w = tid >> 6;
    const int wm = w >> 2, wn = w & 3;
    const int l15 = lane & 15, l16 = lane >> 4;

    const int swzg  = (l16 ^ ((l15 >> 1) & 3)) * 8;
    const int aBase = (wm * 128 + l15) * 32 + swzg;          // + mf*512
    const int bBase = 16384 + (wn * 64 + l15) * 32 + swzg;   // + nf*512

    const int gsw = ((tid & 3) ^ ((tid >> 3) & 3)) * 8;
    const u16* pA = A + (size_t)(c0 + (tid >> 2)) * KLD + gsw;
    const u16* pB = B + (size_t)(nt0 + (tid >> 2)) * KLD + gsw;
    u16* const ldsW = &lds[w * 512];

#define STG(op, d, ks, tt) do {                                               \
    const u16* s_ = ((op) ? pB : pA) + (size_t)(tt) * 64 + (ks) * 32;         \
    GLOAD16(s_, ldsW + (d) * 32768 + (op) * 16384 + (ks) * 8192);             \
    GLOAD16(s_ + (size_t)128 * KLD,                                           \
            ldsW + (d) * 32768 + (op) * 16384 + (ks) * 8192 + 4096);          \
} while (0)

#define PH(d, ks, mh, LOADB, STAGE_STMT, WAIT_STMT) do {                      \
    short8 a_[4];                                                             \
    _Pragma("unroll")                                                         \
    for (int mf = 0; mf < 4; ++mf)                                            \
        a_[mf] = *(const short8*)&lds[(d) * 32768 + (ks) * 8192 + aBase       \
                                      + ((mh) * 4 + mf) * 512];               \
    if (LOADB) {                                                              \
        _Pragma("unroll")                                                     \
        for (int nf = 0; nf < 4; ++nf)                                        \
            bcur[nf] = *(const short8*)&lds[(d) * 32768 + (ks) * 8192 + bBase \
                                            + nf * 512];                      \
    }                                                                         \
    STAGE_STMT;                                                               \
    __builtin_amdgcn_s_barrier();                                             \
    asm volatile("s_waitcnt lgkmcnt(0)" ::: "memory");                        \
    __builtin_amdgcn_sched_barrier(0);                                        \
    __builtin_amdgcn_s_setprio(1);                                            \
    _Pragma("unroll")                                                         \
    for (int mf = 0; mf < 4; ++mf)                                            \
        _Pragma("unroll")                                                     \
        for (int nf = 0; nf < 4; ++nf)                                        \
            acc[(mh) * 4 + mf][nf] = __builtin_amdgcn_mfma_f32_16x16x32_bf16( \
                a_[mf], bcur[nf], acc[(mh) * 4 + mf][nf], 0, 0, 0);           \
    __builtin_amdgcn_s_setprio(0);                                            \
    WAIT_STMT;                                                                \
    __builtin_amdgcn_s_barrier();                                             \
    asm volatile("" ::: "memory");                                            \
} while (0)

    f32x4 acc[8][4];
    #pragma unroll
    for (int i = 0; i < 8; ++i)
        #pragma unroll
        for (int j = 0; j < 4; ++j)
            acc[i][j] = (f32x4){0.f, 0.f, 0.f, 0.f};

    // prologue: tile0 all 4 units (d0), tile1 A-ks0/B-ks0/B-ks1 (d1)
    STG(0, 0, 0, kt0); STG(1, 0, 0, kt0); STG(0, 0, 1, kt0); STG(1, 0, 1, kt0);
    STG(0, 1, 0, kt0 + 1); STG(1, 1, 0, kt0 + 1); STG(1, 1, 1, kt0 + 1);
    asm volatile("s_waitcnt vmcnt(0)" ::: "memory");
    __builtin_amdgcn_s_barrier();
    asm volatile("" ::: "memory");

    const int I = nk >> 1;
    for (int i = 0; i < I; ++i) {
        const int t = kt0 + 2 * i;
        const bool pf = (i < I - 1);
        short8 bcur[4];
        // tile t (dbuf 0)
        PH(0, 0, 0, 1, { STG(0, 1, 1, t + 1); }, );
        PH(0, 0, 1, 0, { if (pf) STG(1, 0, 0, t + 2); }, );
        PH(0, 1, 0, 1, { if (pf) STG(0, 0, 0, t + 2); }, );
        PH(0, 1, 1, 0, { if (pf) STG(1, 0, 1, t + 2); },
           { if (pf) asm volatile("s_waitcnt vmcnt(6)" ::: "memory");
             else    asm volatile("s_waitcnt vmcnt(0)" ::: "memory"); });
        // tile t+1 (dbuf 1)
        PH(1, 0, 0, 1, { if (pf) STG(0, 0, 1, t + 2); }, );
        PH(1, 0, 1, 0, { if (pf) STG(1, 1, 0, t + 3); }, );
        PH(1, 1, 0, 1, { if (pf) STG(0, 1, 0, t + 3); }, );
        PH(1, 1, 1, 0, { if (pf) STG(1, 1, 1, t + 3); },
           { if (pf) asm volatile("s_waitcnt vmcnt(6)" ::: "memory");
             else    asm volatile("s_waitcnt vmcnt(0)" ::: "memory"); });
    }

    // fold-epilogue: channel col = bx*128 + wm*64 + j*16 + l16*4 (q=l16*4+reg)
    const int Mout = M2 >> 1;
    #pragma unroll
    for (int j = 0; j < 4; ++j) {
        const int cg = bx * 128 + wm * 64 + j * 16 + l16 * 4;
        #pragma unroll
        for (int nf = 0; nf < 4; ++nf) {
            const int nt = nt0 + wn * 64 + nf * 16 + l15;
            f32x4 s = acc[2 * j][nf] + acc[2 * j + 1][nf];
            *(f32x4*)&X[(size_t)nt * Mout + cg] = s;
        }
    }
#undef STG
#undef PH
}

// layer-1 fused: f<400 -> vis (panel co-location map), else tact.
__global__ __launch_bounds__(512, 2) void gemm_l1(
    const u16* __restrict__ Av, const u16* __restrict__ Bv, float* __restrict__ Xv,
    const u16* __restrict__ At, const u16* __restrict__ Bt, float* __restrict__ Xt)
{
    __shared__ u16 lds[65536];
    const int f = blockIdx.x + 4 * (blockIdx.y + 50 * blockIdx.z); // grid (4,50,3)
    if (f < 400) {
        // co-location: panel (by,bz) mates bx=0..3 at f = 16m+2p+{0,1,8,9}
        const int p   = (f & 7) >> 1;              // XCD-pair 0..3
        const int k   = ((f >> 3) << 1) | (f & 1); // 0..99
        const int bx  = k & 3;
        const int pi  = 25 * p + (k >> 2);         // 0..99
        const int by  = pi % 50;
        const int bz  = pi / 50;
        gemm_core(Av, Bv, Xv + (size_t)bz * 12800 * 512, 1024, 6400,
                  bz * 50, 50, bx, by, lds);
    } else {
        const int f2 = f - 400;
        gemm_core(At, Bt, Xt, 1024, 256, 0, 4, f2 & 3, f2 >> 2, lds);
    }
}

// generic (combi): simple bijective XCD swizzle.
__global__ __launch_bounds__(512, 2) void gemm_g(
    const u16* __restrict__ A, const u16* __restrict__ B,
    float* __restrict__ Xbase, int M2, int KLD, int ktPerZ)
{
    __shared__ u16 lds[65536];
    const int Dx = gridDim.x, Dy = gridDim.y;
    int f = blockIdx.x + Dx * (blockIdx.y + Dy * blockIdx.z);
    const int nwg = Dx * Dy * gridDim.z;
    f = (f & 7) * (nwg >> 3) + (f >> 3);
    const int bx = f % Dx;
    const int by = (f / Dx) % Dy;
    const int bz = f / (Dx * Dy);
    gemm_core(A, B, Xbase + (size_t)bz * 12800 * (M2 >> 1), M2, KLD,
              bz * ktPerZ, ktPerZ, bx, by, lds);
}

// ---------------- Loihi scans (16-deep pipelined loads) ----------------
__device__ __forceinline__ float loihi_step(float xt, float& u, float& v)
{
    u = truncf(u * 0.75f) + 64.f * xt;
    v = truncf(v * 0.96875f) + u;
    if (v >= 5120.f) { v = 0.f; return 1.f; }
    return 0.f;
}

// scan_ab: tact Xt[nt][512] (folded) + vis Xv[2][nt][512] (folded, 2 z) -> Sc
__global__ __launch_bounds__(64) void scan_ab(const float* __restrict__ Xt,
                                              const float* __restrict__ Xv,
                                              u16* __restrict__ Sc)
{
    const int gid = blockIdx.x * 64 + threadIdx.x;   // 32*1024 threads
    const int n = gid >> 10;
    const int c = gid & 1023;
    const size_t PS = (size_t)12800 * 512;

    u16* srow = Sc + (size_t)(n * 400) * 1024 + c;
    srow[0] = 0;

    float buf[16];
    float u = 0.f, v = 0.f;

    if (c < 512) {
        const float* xr = Xt + (size_t)(n * 400) * 512 + c;
        #pragma unroll
        for (int d = 0; d < 16; ++d) buf[d] = xr[(size_t)d * 512];
        #pragma unroll 16
        for (int t = 0; t < 400; ++t) {
            const float xt = buf[t & 15];
            const int tn = t + 16;
            buf[t & 15] = (tn < 400) ? xr[(size_t)tn * 512] : 0.f;
            const float sp = loihi_step(xt, u, v);
            if (t < 399) srow[(size_t)(t + 1) * 1024] = (sp != 0.f) ? (u16)0x3F80 : (u16)0;
        }
    } else {
        const float* xr = Xv + (size_t)(n * 400) * 512 + (c - 512);
        #pragma unroll
        for (int d = 0; d < 16; ++d) {
            const size_t o = (size_t)d * 512;
            buf[d] = xr[o] + xr[o + PS];
        }
        #pragma unroll 16
        for (int t = 0; t < 400; ++t) {
            const float xt = buf[t & 15];
            const int tn = t + 16;
            float nx = 0.f;
            if (tn < 400) {
                const size_t o = (size_t)tn * 512;
                nx = xr[o] + xr[o + PS];
            }
            buf[t & 15] = nx;
            const float sp = loihi_step(xt, u, v);
            if (t < 399) srow[(size_t)(t + 1) * 1024] = (sp != 0.f) ? (u16)0x3F80 : (u16)0;
        }
    }
}

// scan_c: combi Xc[2][nt][256] (folded, 2 z) -> out [n][c][t]
__global__ __launch_bounds__(64) void scan_c(const float* __restrict__ Xc,
                                             float* __restrict__ out)
{
    const int gid = blockIdx.x * 64 + threadIdx.x;   // 32*256 threads
    const int n = gid >> 8;
    const int c = gid & 255;
    const size_t PS = (size_t)12800 * 256;
    const float* xr = Xc + (size_t)(n * 400) * 256 + c;
    float* orow = out + ((size_t)n * 256 + c) * 400;
    orow[0] = 0.f;

    float buf[16];
    #pragma unroll
    for (int d = 0; d < 16; ++d) {
        const size_t o = (size_t)d * 256;
        buf[d] = xr[o] + xr[o + PS];
    }
    float u = 0.f, v = 0.f;
    #pragma unroll 16
    for (int t = 0; t < 400; ++t) {
        const float xt = buf[t & 15];
        const int tn = t + 16;
        float nx = 0.f;
        if (tn < 400) {
            const size_t o = (size_t)tn * 256;
            nx = xr[o] + xr[o + PS];
        }
        buf[t & 15] = nx;
        const float sp = loihi_step(xt, u, v);
        if (t < 399) orow[t + 1] = sp;
    }
}

extern "C" void kernel_launch(void* const* d_in, const int* in_sizes, int n_in,
                              void* d_out, int out_size, void* d_ws, size_t ws_size,
                              hipStream_t stream)
{
    const float* tact   = (const float*)d_in[0];  // [32][156][400]
    const float* vis    = (const float*)d_in[1];  // [32][6300][400]
    const float* W_tact = (const float*)d_in[2];  // [512][156]
    const float* W_vis  = (const float*)d_in[3];  // [512][6300]
    const float* W_comb = (const float*)d_in[4];  // [256][1024]
    float* out = (float*)d_out;                   // [32][256][400]

    const int NT = 32 * 400;            // 12800
    const int Ktp = 256;                // tact K pad: 4 K-tiles of 64
    const int Kvp = 6400;               // vis K pad: 100 K-tiles
    const int Kc  = 1024;               // combi K: 16 K-tiles

    // ---- workspace carve-up: ~264 MB ----
    char* p = (char*)d_ws;
    u16* Sv  = (u16*)p;                p += (size_t)NT * Kvp * 2;        // 163.8MB
    u16* St  = (u16*)p;                p += (size_t)NT * Ktp * 2;        //   6.6MB
    u16* Wt2 = (u16*)p;                p += (size_t)1024 * Ktp * 2;      //   0.5MB
    u16* Wv2 = (u16*)p;                p += (size_t)1024 * Kvp * 2;      //  13.1MB
    u16* Wc2 = (u16*)p;                p += (size_t)512 * Kc * 2;        //   1.0MB
    float* Xv = (float*)p;             p += (size_t)2 * NT * 512 * 4;    //  52.4MB
    float* Xt = (float*)p;             p += (size_t)NT * 512 * 4;        //  26.2MB
    // aliases into Sv region (Sv dead after gemm_l1 completes):
    u16*   Sc = (u16*)Sv;                                          // [NT][1024] bf16
    float* Xc = (float*)((char*)Sv + (size_t)NT * 1024 * 2);       // [2][NT][256] f32

    // 1) weight splits (interleaved 2 RNE planes)
    split_w2s<<<dim3(Kvp / 256, 512), 256, 0, stream>>>(W_vis,  Wv2, 512, 6300, Kvp);
    split_w2s<<<dim3(Ktp / 256, 512), 256, 0, stream>>>(W_tact, Wt2, 512, 156,  Ktp);
    split_w2s<<<dim3(Kc  / 256, 256), 256, 0, stream>>>(W_comb, Wc2, 256, 1024, Kc);

    // 2) spike transpose+convert
    cvt_sp<<<dim3(7, Kvp / 64, 32), 256, 0, stream>>>(vis,  Sv, 6300, Kvp);
    cvt_sp<<<dim3(7, Ktp / 64, 32), 256, 0, stream>>>(tact, St, 156,  Ktp);

    // 3) fused layer-1 GEMM: vis (co-located, z=0..1) + tact (z=2)
    gemm_l1<<<dim3(4, 50, 3), 512, 0, stream>>>(Wv2, Sv, Xv, Wt2, St, Xt);

    // 4) scan layers 1+2 -> combi spikes (bf16, [nt][1024])
    scan_ab<<<dim3((32 * 1024) / 64), 64, 0, stream>>>(Xt, Xv, Sc);

    // 5) combi GEMM (z=2 chunks of 8 K-tiles) + scan -> out
    gemm_g<<<dim3(2, 50, 2), 512, 0, stream>>>(Wc2, Sc, Xc, 512, Kc, 8);
    scan_c<<<dim3((32 * 256) / 64), 64, 0, stream>>>(Xc, out);

    (void)in_sizes; (void)n_in; (void)out_size; (void)ws_size;
}

// Round 12
// 586.006 us; speedup vs baseline: 1.1714x; 1.0166x over previous
//
#include <hip/hip_runtime.h>

// Loihi SNN, 3 layers of (GEMM -> Loihi scan -> delay).
// Round 12: front-end consolidation.
//  - ONE `prep` kernel fuses {W splits x3 + spike transpose x2}: splits and
//    tact-cvt hide under vis-cvt; 9 -> 5 launches.
//  - cvt LDS tile row stride 80 -> 88 u16 (176 B): fixes an 8-way
//    ds_write_b16 bank cluster (160 B stride put all lanes in banks 0-7);
//    176 B keeps 16 B alignment for the b128 read phase.
//  - gemm_l1 (8-phase template, co-location map, fold-epilogue), gemm_g,
//    scans: byte-identical to round 11.

typedef unsigned short u16;
typedef unsigned int u32;
typedef __attribute__((ext_vector_type(8))) short short8;
typedef __attribute__((ext_vector_type(4))) float f32x4;

#define GLOAD16(g, l)                                                         \
    __builtin_amdgcn_global_load_lds(                                         \
        (const __attribute__((address_space(1))) u32*)(g),                    \
        (__attribute__((address_space(3))) u32*)(l), 16, 0, 0)

__device__ __forceinline__ u16 f2bf_trunc(float x) {
    return (u16)(__float_as_uint(x) >> 16);
}

// ---------------- fused prep: W splits + spike transposes ----------------
__device__ __forceinline__ void cvt_body(const float* __restrict__ S,
                                         u16* __restrict__ Sp,
                                         int I, int KLD, int n, int i0, int t0,
                                         u16 (*tile)[88])
{
    const int tid = threadIdx.x;
    const int il = tid >> 2;
    const int q  = tid & 3;
    const int gi = i0 + il;
    const bool iok = gi < I;
    const float* srow = S + ((size_t)n * I + gi) * 400 + t0;

    #pragma unroll
    for (int s = 0; s < 4; ++s) {
        const int fi = s * 4 + q;
        const int tl = fi * 4;
        float4 v = make_float4(0.f, 0.f, 0.f, 0.f);
        if (iok && (t0 + tl) < 400)
            v = *(const float4*)(srow + tl);
        tile[tl + 0][il] = f2bf_trunc(v.x);
        tile[tl + 1][il] = f2bf_trunc(v.y);
        tile[tl + 2][il] = f2bf_trunc(v.z);
        tile[tl + 3][il] = f2bf_trunc(v.w);
    }
    __syncthreads();

    const int tl = tid >> 2;
    const int iq = tid & 3;
    const int t  = t0 + tl;
    const int go = i0 + iq * 16;
    if (t < 400 && go < KLD) {
        u16* dst = Sp + (size_t)(n * 400 + t) * KLD + go;
        *(short8*)(dst)     = *(const short8*)&tile[tl][iq * 16];
        *(short8*)(dst + 8) = *(const short8*)&tile[tl][iq * 16 + 8];
    }
}

__device__ __forceinline__ void split_one(const float* __restrict__ W,
                                          u16* __restrict__ W2,
                                          int C, int K, int KLD, int idx)
{
    const int c = idx / KLD;
    const int k = idx - c * KLD;
    float w = (k < K) ? W[(size_t)c * K + k] : 0.f;
    u32 b  = __float_as_uint(w);
    u32 hb = (b + 0x7FFFu + ((b >> 16) & 1u)) & 0xFFFF0000u;
    float r = w - __uint_as_float(hb);
    u32 rb = __float_as_uint(r);
    u32 mb = (rb + 0x7FFFu + ((rb >> 16) & 1u)) & 0xFFFF0000u;
    const int rh = ((c >> 4) << 5) | (c & 15);
    W2[(size_t)rh * KLD + k]        = (u16)(hb >> 16);
    W2[(size_t)(rh + 16) * KLD + k] = (u16)(mb >> 16);
}

// grid: [0,22400) vis cvt | [22400,23296) tact cvt | [23296,24320) splits
__global__ __launch_bounds__(256) void prep(
    const float* __restrict__ vis, const float* __restrict__ tact,
    const float* __restrict__ Wv, const float* __restrict__ Wt,
    const float* __restrict__ Wc,
    u16* __restrict__ Sv, u16* __restrict__ St,
    u16* __restrict__ Wv2, u16* __restrict__ Wt2, u16* __restrict__ Wc2)
{
    __shared__ u16 tile[64][88];
    const int b = blockIdx.x;
    if (b < 22400) {
        const int x = b % 7, y = (b / 7) % 100, n = b / 700;
        cvt_body(vis, Sv, 6300, 6400, n, y * 64, x * 64, tile);
    } else if (b < 23296) {
        const int b2 = b - 22400;
        const int x = b2 % 7, y = (b2 / 7) % 4, n = b2 / 28;
        cvt_body(tact, St, 156, 256, n, y * 64, x * 64, tile);
    } else {
        const int b3 = b - 23296;   // 0..1023
        // element ranges: vis 3,276,800 | tact 131,072 | combi 262,144
        for (int e = b3 * 256 + (int)threadIdx.x; e < 3670016; e += 1024 * 256) {
            if (e < 3276800)        split_one(Wv, Wv2, 512, 6300, 6400, e);
            else if (e < 3407872)   split_one(Wt, Wt2, 512, 156,  256,  e - 3276800);
            else                    split_one(Wc, Wc2, 256, 1024, 1024, e - 3407872);
        }
    }
}

// ---------------- 8-phase GEMM core (r10 template, fold-epilogue) ----------
__device__ __forceinline__ void gemm_core(
    const u16* __restrict__ A, const u16* __restrict__ B,
    float* __restrict__ X, int M2, int KLD, int kt0, int nk,
    int bx, int by, u16* lds)
{
    const int c0  = bx * 256;
    const int nt0 = by * 256;
    const int tid  = threadIdx.x;
    const int lane = tid & 63, w = tid >> 6;
    const int wm = w >> 2, wn = w & 3;
    const int l15 = lane & 15, l16 = lane >> 4;

    const int swzg  = (l16 ^ ((l15 >> 1) & 3)) * 8;
    const int aBase = (wm * 128 + l15) * 32 + swzg;          // + mf*512
    const int bBase = 16384 + (wn * 64 + l15) * 32 + swzg;   // + nf*512

    const int gsw = ((tid & 3) ^ ((tid >> 3) & 3)) * 8;
    const u16* pA = A + (size_t)(c0 + (tid >> 2)) * KLD + gsw;
    const u16* pB = B + (size_t)(nt0 + (tid >> 2)) * KLD + gsw;
    u16* const ldsW = &lds[w * 512];

#define STG(op, d, ks, tt) do {                                               \
    const u16* s_ = ((op) ? pB : pA) + (size_t)(tt) * 64 + (ks) * 32;         \
    GLOAD16(s_, ldsW + (d) * 32768 + (op) * 16384 + (ks) * 8192);             \
    GLOAD16(s_ + (size_t)128 * KLD,                                           \
            ldsW + (d) * 32768 + (op) * 16384 + (ks) * 8192 + 4096);          \
} while (0)

#define PH(d, ks, mh, LOADB, STAGE_STMT, WAIT_STMT) do {                      \
    short8 a_[4];                                                             \
    _Pragma("unroll")                                                         \
    for (int mf = 0; mf < 4; ++mf)                                            \
        a_[mf] = *(const short8*)&lds[(d) * 32768 + (ks) * 8192 + aBase       \
                                      + ((mh) * 4 + mf) * 512];               \
    if (LOADB) {                                                              \
        _Pragma("unroll")                                                     \
        for (int nf = 0; nf < 4; ++nf)                                        \
            bcur[nf] = *(const short8*)&lds[(d) * 32768 + (ks) * 8192 + bBase \
                                            + nf * 512];                      \
    }                                                                         \
    STAGE_STMT;                                                               \
    __builtin_amdgcn_s_barrier();                                             \
    asm volatile("s_waitcnt lgkmcnt(0)" ::: "memory");                        \
    __builtin_amdgcn_sched_barrier(0);                                        \
    __builtin_amdgcn_s_setprio(1);                                            \
    _Pragma("unroll")                                                         \
    for (int mf = 0; mf < 4; ++mf)                                            \
        _Pragma("unroll")                                                     \
        for (int nf = 0; nf < 4; ++nf)                                        \
            acc[(mh) * 4 + mf][nf] = __builtin_amdgcn_mfma_f32_16x16x32_bf16( \
                a_[mf], bcur[nf], acc[(mh) * 4 + mf][nf], 0, 0, 0);           \
    __builtin_amdgcn_s_setprio(0);                                            \
    WAIT_STMT;                                                                \
    __builtin_amdgcn_s_barrier();                                             \
    asm volatile("" ::: "memory");                                            \
} while (0)

    f32x4 acc[8][4];
    #pragma unroll
    for (int i = 0; i < 8; ++i)
        #pragma unroll
        for (int j = 0; j < 4; ++j)
            acc[i][j] = (f32x4){0.f, 0.f, 0.f, 0.f};

    // prologue: tile0 all 4 units (d0), tile1 A-ks0/B-ks0/B-ks1 (d1)
    STG(0, 0, 0, kt0); STG(1, 0, 0, kt0); STG(0, 0, 1, kt0); STG(1, 0, 1, kt0);
    STG(0, 1, 0, kt0 + 1); STG(1, 1, 0, kt0 + 1); STG(1, 1, 1, kt0 + 1);
    asm volatile("s_waitcnt vmcnt(0)" ::: "memory");
    __builtin_amdgcn_s_barrier();
    asm volatile("" ::: "memory");

    const int I = nk >> 1;
    for (int i = 0; i < I; ++i) {
        const int t = kt0 + 2 * i;
        const bool pf = (i < I - 1);
        short8 bcur[4];
        // tile t (dbuf 0)
        PH(0, 0, 0, 1, { STG(0, 1, 1, t + 1); }, );
        PH(0, 0, 1, 0, { if (pf) STG(1, 0, 0, t + 2); }, );
        PH(0, 1, 0, 1, { if (pf) STG(0, 0, 0, t + 2); }, );
        PH(0, 1, 1, 0, { if (pf) STG(1, 0, 1, t + 2); },
           { if (pf) asm volatile("s_waitcnt vmcnt(6)" ::: "memory");
             else    asm volatile("s_waitcnt vmcnt(0)" ::: "memory"); });
        // tile t+1 (dbuf 1)
        PH(1, 0, 0, 1, { if (pf) STG(0, 0, 1, t + 2); }, );
        PH(1, 0, 1, 0, { if (pf) STG(1, 1, 0, t + 3); }, );
        PH(1, 1, 0, 1, { if (pf) STG(0, 1, 0, t + 3); }, );
        PH(1, 1, 1, 0, { if (pf) STG(1, 1, 1, t + 3); },
           { if (pf) asm volatile("s_waitcnt vmcnt(6)" ::: "memory");
             else    asm volatile("s_waitcnt vmcnt(0)" ::: "memory"); });
    }

    // fold-epilogue: channel col = bx*128 + wm*64 + j*16 + l16*4
    const int Mout = M2 >> 1;
    #pragma unroll
    for (int j = 0; j < 4; ++j) {
        const int cg = bx * 128 + wm * 64 + j * 16 + l16 * 4;
        #pragma unroll
        for (int nf = 0; nf < 4; ++nf) {
            const int nt = nt0 + wn * 64 + nf * 16 + l15;
            f32x4 s = acc[2 * j][nf] + acc[2 * j + 1][nf];
            *(f32x4*)&X[(size_t)nt * Mout + cg] = s;
        }
    }
#undef STG
#undef PH
}

// layer-1 fused: f<400 -> vis (panel co-location map), else tact.
__global__ __launch_bounds__(512, 2) void gemm_l1(
    const u16* __restrict__ Av, const u16* __restrict__ Bv, float* __restrict__ Xv,
    const u16* __restrict__ At, const u16* __restrict__ Bt, float* __restrict__ Xt)
{
    __shared__ u16 lds[65536];
    const int f = blockIdx.x + 4 * (blockIdx.y + 50 * blockIdx.z); // grid (4,50,3)
    if (f < 400) {
        // co-location: panel (by,bz) mates bx=0..3 at f = 16m+2p+{0,1,8,9}
        const int p   = (f & 7) >> 1;              // XCD-pair 0..3
        const int k   = ((f >> 3) << 1) | (f & 1); // 0..99
        const int bx  = k & 3;
        const int pi  = 25 * p + (k >> 2);         // 0..99
        const int by  = pi % 50;
        const int bz  = pi / 50;
        gemm_core(Av, Bv, Xv + (size_t)bz * 12800 * 512, 1024, 6400,
                  bz * 50, 50, bx, by, lds);
    } else {
        const int f2 = f - 400;
        gemm_core(At, Bt, Xt, 1024, 256, 0, 4, f2 & 3, f2 >> 2, lds);
    }
}

// generic (combi): simple bijective XCD swizzle.
__global__ __launch_bounds__(512, 2) void gemm_g(
    const u16* __restrict__ A, const u16* __restrict__ B,
    float* __restrict__ Xbase, int M2, int KLD, int ktPerZ)
{
    __shared__ u16 lds[65536];
    const int Dx = gridDim.x, Dy = gridDim.y;
    int f = blockIdx.x + Dx * (blockIdx.y + Dy * blockIdx.z);
    const int nwg = Dx * Dy * gridDim.z;
    f = (f & 7) * (nwg >> 3) + (f >> 3);
    const int bx = f % Dx;
    const int by = (f / Dx) % Dy;
    const int bz = f / (Dx * Dy);
    gemm_core(A, B, Xbase + (size_t)bz * 12800 * (M2 >> 1), M2, KLD,
              bz * ktPerZ, ktPerZ, bx, by, lds);
}

// ---------------- Loihi scans (16-deep pipelined loads) ----------------
__device__ __forceinline__ float loihi_step(float xt, float& u, float& v)
{
    u = truncf(u * 0.75f) + 64.f * xt;
    v = truncf(v * 0.96875f) + u;
    if (v >= 5120.f) { v = 0.f; return 1.f; }
    return 0.f;
}

// scan_ab: tact Xt[nt][512] (folded) + vis Xv[2][nt][512] (folded, 2 z) -> Sc
__global__ __launch_bounds__(64) void scan_ab(const float* __restrict__ Xt,
                                              const float* __restrict__ Xv,
                                              u16* __restrict__ Sc)
{
    const int gid = blockIdx.x * 64 + threadIdx.x;   // 32*1024 threads
    const int n = gid >> 10;
    const int c = gid & 1023;
    const size_t PS = (size_t)12800 * 512;

    u16* srow = Sc + (size_t)(n * 400) * 1024 + c;
    srow[0] = 0;

    float buf[16];
    float u = 0.f, v = 0.f;

    if (c < 512) {
        const float* xr = Xt + (size_t)(n * 400) * 512 + c;
        #pragma unroll
        for (int d = 0; d < 16; ++d) buf[d] = xr[(size_t)d * 512];
        #pragma unroll 16
        for (int t = 0; t < 400; ++t) {
            const float xt = buf[t & 15];
            const int tn = t + 16;
            buf[t & 15] = (tn < 400) ? xr[(size_t)tn * 512] : 0.f;
            const float sp = loihi_step(xt, u, v);
            if (t < 399) srow[(size_t)(t + 1) * 1024] = (sp != 0.f) ? (u16)0x3F80 : (u16)0;
        }
    } else {
        const float* xr = Xv + (size_t)(n * 400) * 512 + (c - 512);
        #pragma unroll
        for (int d = 0; d < 16; ++d) {
            const size_t o = (size_t)d * 512;
            buf[d] = xr[o] + xr[o + PS];
        }
        #pragma unroll 16
        for (int t = 0; t < 400; ++t) {
            const float xt = buf[t & 15];
            const int tn = t + 16;
            float nx = 0.f;
            if (tn < 400) {
                const size_t o = (size_t)tn * 512;
                nx = xr[o] + xr[o + PS];
            }
            buf[t & 15] = nx;
            const float sp = loihi_step(xt, u, v);
            if (t < 399) srow[(size_t)(t + 1) * 1024] = (sp != 0.f) ? (u16)0x3F80 : (u16)0;
        }
    }
}

// scan_c: combi Xc[2][nt][256] (folded, 2 z) -> out [n][c][t]
__global__ __launch_bounds__(64) void scan_c(const float* __restrict__ Xc,
                                             float* __restrict__ out)
{
    const int gid = blockIdx.x * 64 + threadIdx.x;   // 32*256 threads
    const int n = gid >> 8;
    const int c = gid & 255;
    const size_t PS = (size_t)12800 * 256;
    const float* xr = Xc + (size_t)(n * 400) * 256 + c;
    float* orow = out + ((size_t)n * 256 + c) * 400;
    orow[0] = 0.f;

    float buf[16];
    #pragma unroll
    for (int d = 0; d < 16; ++d) {
        const size_t o = (size_t)d * 256;
        buf[d] = xr[o] + xr[o + PS];
    }
    float u = 0.f, v = 0.f;
    #pragma unroll 16
    for (int t = 0; t < 400; ++t) {
        const float xt = buf[t & 15];
        const int tn = t + 16;
        float nx = 0.f;
        if (tn < 400) {
            const size_t o = (size_t)tn * 256;
            nx = xr[o] + xr[o + PS];
        }
        buf[t & 15] = nx;
        const float sp = loihi_step(xt, u, v);
        if (t < 399) orow[t + 1] = sp;
    }
}

extern "C" void kernel_launch(void* const* d_in, const int* in_sizes, int n_in,
                              void* d_out, int out_size, void* d_ws, size_t ws_size,
                              hipStream_t stream)
{
    const float* tact   = (const float*)d_in[0];  // [32][156][400]
    const float* vis    = (const float*)d_in[1];  // [32][6300][400]
    const float* W_tact = (const float*)d_in[2];  // [512][156]
    const float* W_vis  = (const float*)d_in[3];  // [512][6300]
    const float* W_comb = (const float*)d_in[4];  // [256][1024]
    float* out = (float*)d_out;                   // [32][256][400]

    const int NT = 32 * 400;            // 12800
    const int Ktp = 256;                // tact K pad: 4 K-tiles of 64
    const int Kvp = 6400;               // vis K pad: 100 K-tiles
    const int Kc  = 1024;               // combi K: 16 K-tiles

    // ---- workspace carve-up: ~264 MB (identical to round 11) ----
    char* p = (char*)d_ws;
    u16* Sv  = (u16*)p;                p += (size_t)NT * Kvp * 2;        // 163.8MB
    u16* St  = (u16*)p;                p += (size_t)NT * Ktp * 2;        //   6.6MB
    u16* Wt2 = (u16*)p;                p += (size_t)1024 * Ktp * 2;      //   0.5MB
    u16* Wv2 = (u16*)p;                p += (size_t)1024 * Kvp * 2;      //  13.1MB
    u16* Wc2 = (u16*)p;                p += (size_t)512 * Kc * 2;        //   1.0MB
    float* Xv = (float*)p;             p += (size_t)2 * NT * 512 * 4;    //  52.4MB
    float* Xt = (float*)p;             p += (size_t)NT * 512 * 4;        //  26.2MB
    // aliases into Sv region (Sv dead after gemm_l1 completes):
    u16*   Sc = (u16*)Sv;                                          // [NT][1024] bf16
    float* Xc = (float*)((char*)Sv + (size_t)NT * 1024 * 2);       // [2][NT][256] f32

    // 1) fused prep: all W splits + both spike transposes (one launch)
    prep<<<dim3(24320), 256, 0, stream>>>(vis, tact, W_vis, W_tact, W_comb,
                                          Sv, St, Wv2, Wt2, Wc2);

    // 2) fused layer-1 GEMM: vis (co-located, z=0..1) + tact (z=2)
    gemm_l1<<<dim3(4, 50, 3), 512, 0, stream>>>(Wv2, Sv, Xv, Wt2, St, Xt);

    // 3) scan layers 1+2 -> combi spikes (bf16, [nt][1024])
    scan_ab<<<dim3((32 * 1024) / 64), 64, 0, stream>>>(Xt, Xv, Sc);

    // 4) combi GEMM (z=2 chunks of 8 K-tiles) + scan -> out
    gemm_g<<<dim3(2, 50, 2), 512, 0, stream>>>(Wc2, Sc, Xc, 512, Kc, 8);
    scan_c<<<dim3((32 * 256) / 64), 64, 0, stream>>>(Xc, out);

    (void)in_sizes; (void)n_in; (void)out_size; (void)ws_size;
}

// Round 13
// 397.394 us; speedup vs baseline: 1.7274x; 1.4746x over previous
//
#include <hip/hip_runtime.h>

// Loihi SNN, 3 layers of (GEMM -> Loihi scan -> delay).
// Round 13:
//  - gemm_l1 vis K-split z=4 (chunks 26/26/26/22 K-tiles): 1000 shorter
//    blocks -> drain tail shrinks. Co-location map: bz = XCD-pair (each
//    pair owns one K-chunk; mates f = 16*by + 2*bz + {0,1,8,9}).
//  - BW-optimal pre-reduce kernels fold all partials: Xall[nt][1024]
//    (tact | sum of 4 vis partials), Xc2[nt][256] (sum of 2 combi partials)
//    -> scans read ONE stream.
//  - scans: 3-buffer block pipeline (cur/nx1/nx2 x16, static indices) =
//    depth-32 prefetch, 48 vmem in flight <= 63, slack ~900+ cy.
//  - workspace 316 MB (ws is ~1.29 GB per the poison-fill evidence).

typedef unsigned short u16;
typedef unsigned int u32;
typedef __attribute__((ext_vector_type(8))) short short8;
typedef __attribute__((ext_vector_type(4))) float f32x4;

#define GLOAD16(g, l)                                                         \
    __builtin_amdgcn_global_load_lds(                                         \
        (const __attribute__((address_space(1))) u32*)(g),                    \
        (__attribute__((address_space(3))) u32*)(l), 16, 0, 0)

__device__ __forceinline__ u16 f2bf_trunc(float x) {
    return (u16)(__float_as_uint(x) >> 16);
}

// ---------------- fused prep: W splits + spike transposes ----------------
__device__ __forceinline__ void cvt_body(const float* __restrict__ S,
                                         u16* __restrict__ Sp,
                                         int I, int KLD, int n, int i0, int t0,
                                         u16 (*tile)[88])
{
    const int tid = threadIdx.x;
    const int il = tid >> 2;
    const int q  = tid & 3;
    const int gi = i0 + il;
    const bool iok = gi < I;
    const float* srow = S + ((size_t)n * I + gi) * 400 + t0;

    #pragma unroll
    for (int s = 0; s < 4; ++s) {
        const int fi = s * 4 + q;
        const int tl = fi * 4;
        float4 v = make_float4(0.f, 0.f, 0.f, 0.f);
        if (iok && (t0 + tl) < 400)
            v = *(const float4*)(srow + tl);
        tile[tl + 0][il] = f2bf_trunc(v.x);
        tile[tl + 1][il] = f2bf_trunc(v.y);
        tile[tl + 2][il] = f2bf_trunc(v.z);
        tile[tl + 3][il] = f2bf_trunc(v.w);
    }
    __syncthreads();

    const int tl = tid >> 2;
    const int iq = tid & 3;
    const int t  = t0 + tl;
    const int go = i0 + iq * 16;
    if (t < 400 && go < KLD) {
        u16* dst = Sp + (size_t)(n * 400 + t) * KLD + go;
        *(short8*)(dst)     = *(const short8*)&tile[tl][iq * 16];
        *(short8*)(dst + 8) = *(const short8*)&tile[tl][iq * 16 + 8];
    }
}

__device__ __forceinline__ void split_one(const float* __restrict__ W,
                                          u16* __restrict__ W2,
                                          int C, int K, int KLD, int idx)
{
    const int c = idx / KLD;
    const int k = idx - c * KLD;
    float w = (k < K) ? W[(size_t)c * K + k] : 0.f;
    u32 b  = __float_as_uint(w);
    u32 hb = (b + 0x7FFFu + ((b >> 16) & 1u)) & 0xFFFF0000u;
    float r = w - __uint_as_float(hb);
    u32 rb = __float_as_uint(r);
    u32 mb = (rb + 0x7FFFu + ((rb >> 16) & 1u)) & 0xFFFF0000u;
    const int rh = ((c >> 4) << 5) | (c & 15);
    W2[(size_t)rh * KLD + k]        = (u16)(hb >> 16);
    W2[(size_t)(rh + 16) * KLD + k] = (u16)(mb >> 16);
}

// grid: [0,22400) vis cvt | [22400,23296) tact cvt | [23296,24320) splits
__global__ __launch_bounds__(256) void prep(
    const float* __restrict__ vis, const float* __restrict__ tact,
    const float* __restrict__ Wv, const float* __restrict__ Wt,
    const float* __restrict__ Wc,
    u16* __restrict__ Sv, u16* __restrict__ St,
    u16* __restrict__ Wv2, u16* __restrict__ Wt2, u16* __restrict__ Wc2)
{
    __shared__ u16 tile[64][88];
    const int b = blockIdx.x;
    if (b < 22400) {
        const int x = b % 7, y = (b / 7) % 100, n = b / 700;
        cvt_body(vis, Sv, 6300, 6400, n, y * 64, x * 64, tile);
    } else if (b < 23296) {
        const int b2 = b - 22400;
        const int x = b2 % 7, y = (b2 / 7) % 4, n = b2 / 28;
        cvt_body(tact, St, 156, 256, n, y * 64, x * 64, tile);
    } else {
        const int b3 = b - 23296;   // 0..1023
        for (int e = b3 * 256 + (int)threadIdx.x; e < 3670016; e += 1024 * 256) {
            if (e < 3276800)        split_one(Wv, Wv2, 512, 6300, 6400, e);
            else if (e < 3407872)   split_one(Wt, Wt2, 512, 156,  256,  e - 3276800);
            else                    split_one(Wc, Wc2, 256, 1024, 1024, e - 3407872);
        }
    }
}

// ---------------- 8-phase GEMM core (fold-epilogue) ----------------
__device__ __forceinline__ void gemm_core(
    const u16* __restrict__ A, const u16* __restrict__ B,
    float* __restrict__ X, int M2, int KLD, int kt0, int nk,
    int bx, int by, u16* lds)
{
    const int c0  = bx * 256;
    const int nt0 = by * 256;
    const int tid  = threadIdx.x;
    const int lane = tid & 63, w = tid >> 6;
    const int wm = w >> 2, wn = w & 3;
    const int l15 = lane & 15, l16 = lane >> 4;

    const int swzg  = (l16 ^ ((l15 >> 1) & 3)) * 8;
    const int aBase = (wm * 128 + l15) * 32 + swzg;          // + mf*512
    const int bBase = 16384 + (wn * 64 + l15) * 32 + swzg;   // + nf*512

    const int gsw = ((tid & 3) ^ ((tid >> 3) & 3)) * 8;
    const u16* pA = A + (size_t)(c0 + (tid >> 2)) * KLD + gsw;
    const u16* pB = B + (size_t)(nt0 + (tid >> 2)) * KLD + gsw;
    u16* const ldsW = &lds[w * 512];

#define STG(op, d, ks, tt) do {                                               \
    const u16* s_ = ((op) ? pB : pA) + (size_t)(tt) * 64 + (ks) * 32;         \
    GLOAD16(s_, ldsW + (d) * 32768 + (op) * 16384 + (ks) * 8192);             \
    GLOAD16(s_ + (size_t)128 * KLD,                                           \
            ldsW + (d) * 32768 + (op) * 16384 + (ks) * 8192 + 4096);          \
} while (0)

#define PH(d, ks, mh, LOADB, STAGE_STMT, WAIT_STMT) do {                      \
    short8 a_[4];                                                             \
    _Pragma("unroll")                                                         \
    for (int mf = 0; mf < 4; ++mf)                                            \
        a_[mf] = *(const short8*)&lds[(d) * 32768 + (ks) * 8192 + aBase       \
                                      + ((mh) * 4 + mf) * 512];               \
    if (LOADB) {                                                              \
        _Pragma("unroll")                                                     \
        for (int nf = 0; nf < 4; ++nf)                                        \
            bcur[nf] = *(const short8*)&lds[(d) * 32768 + (ks) * 8192 + bBase \
                                            + nf * 512];                      \
    }                                                                         \
    STAGE_STMT;                                                               \
    __builtin_amdgcn_s_barrier();                                             \
    asm volatile("s_waitcnt lgkmcnt(0)" ::: "memory");                        \
    __builtin_amdgcn_sched_barrier(0);                                        \
    __builtin_amdgcn_s_setprio(1);                                            \
    _Pragma("unroll")                                                         \
    for (int mf = 0; mf < 4; ++mf)                                            \
        _Pragma("unroll")                                                     \
        for (int nf = 0; nf < 4; ++nf)                                        \
            acc[(mh) * 4 + mf][nf] = __builtin_amdgcn_mfma_f32_16x16x32_bf16( \
                a_[mf], bcur[nf], acc[(mh) * 4 + mf][nf], 0, 0, 0);           \
    __builtin_amdgcn_s_setprio(0);                                            \
    WAIT_STMT;                                                                \
    __builtin_amdgcn_s_barrier();                                             \
    asm volatile("" ::: "memory");                                            \
} while (0)

    f32x4 acc[8][4];
    #pragma unroll
    for (int i = 0; i < 8; ++i)
        #pragma unroll
        for (int j = 0; j < 4; ++j)
            acc[i][j] = (f32x4){0.f, 0.f, 0.f, 0.f};

    // prologue: tile0 all 4 units (d0), tile1 A-ks0/B-ks0/B-ks1 (d1)
    STG(0, 0, 0, kt0); STG(1, 0, 0, kt0); STG(0, 0, 1, kt0); STG(1, 0, 1, kt0);
    STG(0, 1, 0, kt0 + 1); STG(1, 1, 0, kt0 + 1); STG(1, 1, 1, kt0 + 1);
    asm volatile("s_waitcnt vmcnt(0)" ::: "memory");
    __builtin_amdgcn_s_barrier();
    asm volatile("" ::: "memory");

    const int I = nk >> 1;
    for (int i = 0; i < I; ++i) {
        const int t = kt0 + 2 * i;
        const bool pf = (i < I - 1);
        short8 bcur[4];
        // tile t (dbuf 0)
        PH(0, 0, 0, 1, { STG(0, 1, 1, t + 1); }, );
        PH(0, 0, 1, 0, { if (pf) STG(1, 0, 0, t + 2); }, );
        PH(0, 1, 0, 1, { if (pf) STG(0, 0, 0, t + 2); }, );
        PH(0, 1, 1, 0, { if (pf) STG(1, 0, 1, t + 2); },
           { if (pf) asm volatile("s_waitcnt vmcnt(6)" ::: "memory");
             else    asm volatile("s_waitcnt vmcnt(0)" ::: "memory"); });
        // tile t+1 (dbuf 1)
        PH(1, 0, 0, 1, { if (pf) STG(0, 0, 1, t + 2); }, );
        PH(1, 0, 1, 0, { if (pf) STG(1, 1, 0, t + 3); }, );
        PH(1, 1, 0, 1, { if (pf) STG(0, 1, 0, t + 3); }, );
        PH(1, 1, 1, 0, { if (pf) STG(1, 1, 1, t + 3); },
           { if (pf) asm volatile("s_waitcnt vmcnt(6)" ::: "memory");
             else    asm volatile("s_waitcnt vmcnt(0)" ::: "memory"); });
    }

    // fold-epilogue: channel col = bx*128 + wm*64 + j*16 + l16*4
    const int Mout = M2 >> 1;
    #pragma unroll
    for (int j = 0; j < 4; ++j) {
        const int cg = bx * 128 + wm * 64 + j * 16 + l16 * 4;
        #pragma unroll
        for (int nf = 0; nf < 4; ++nf) {
            const int nt = nt0 + wn * 64 + nf * 16 + l15;
            f32x4 s = acc[2 * j][nf] + acc[2 * j + 1][nf];
            *(f32x4*)&X[(size_t)nt * Mout + cg] = s;
        }
    }
#undef STG
#undef PH
}

// layer-1 fused: f<800 -> vis (z=4 K-chunks, co-located), else tact.
__global__ __launch_bounds__(512, 2) void gemm_l1(
    const u16* __restrict__ Av, const u16* __restrict__ Bv, float* __restrict__ Xv,
    const u16* __restrict__ At, const u16* __restrict__ Bt, float* __restrict__ Xt)
{
    __shared__ u16 lds[65536];
    const int f = blockIdx.x + 4 * (blockIdx.y + 50 * blockIdx.z); // grid (4,50,5)
    if (f < 800) {
        // mates of panel (by,bz) at f = 16*by + 2*bz + {0,1,8,9} (XCD pair bz)
        const int k  = ((f >> 3) << 1) | (f & 1);   // 0..199
        const int bx = k & 3;
        const int by = k >> 2;                      // 0..49
        const int bz = (f & 7) >> 1;                // 0..3 (= XCD pair)
        const int kt0 = bz * 26;
        const int nk  = (bz < 3) ? 26 : 22;         // 26+26+26+22 = 100 K-tiles
        gemm_core(Av, Bv, Xv + (size_t)bz * 12800 * 512, 1024, 6400,
                  kt0, nk, bx, by, lds);
    } else {
        const int f2 = f - 800;                     // 0..199
        gemm_core(At, Bt, Xt, 1024, 256, 0, 4, f2 & 3, f2 >> 2, lds);
    }
}

// generic (combi): simple bijective XCD swizzle.
__global__ __launch_bounds__(512, 2) void gemm_g(
    const u16* __restrict__ A, const u16* __restrict__ B,
    float* __restrict__ Xbase, int M2, int KLD, int ktPerZ)
{
    __shared__ u16 lds[65536];
    const int Dx = gridDim.x, Dy = gridDim.y;
    int f = blockIdx.x + Dx * (blockIdx.y + Dy * blockIdx.z);
    const int nwg = Dx * Dy * gridDim.z;
    f = (f & 7) * (nwg >> 3) + (f >> 3);
    const int bx = f % Dx;
    const int by = (f / Dx) % Dy;
    const int bz = f / (Dx * Dy);
    gemm_core(A, B, Xbase + (size_t)bz * 12800 * (M2 >> 1), M2, KLD,
              bz * ktPerZ, ktPerZ, bx, by, lds);
}

// ---------------- pre-reduce kernels (BW-bound, wide) ----------------
// Xall[nt][1024]: c<512 -> Xt[nt][c]; c>=512 -> sum of 4 vis partials.
__global__ __launch_bounds__(256) void reduce_ab(
    const float* __restrict__ Xt, const float* __restrict__ Xv,
    float* __restrict__ Xall)
{
    const size_t PS4 = (size_t)12800 * 128;   // f4 per vis partial
    const f32x4* xt4 = (const f32x4*)Xt;
    const f32x4* xv4 = (const f32x4*)Xv;
    f32x4* o4 = (f32x4*)Xall;
    const size_t total = (size_t)12800 * 256;
    for (size_t i = (size_t)blockIdx.x * 256 + threadIdx.x; i < total;
         i += (size_t)gridDim.x * 256) {
        const size_t nt = i >> 8;
        const int c4 = (int)(i & 255);
        f32x4 v;
        if (c4 < 128) {
            v = xt4[nt * 128 + c4];
        } else {
            const size_t o = nt * 128 + (c4 - 128);
            v = (xv4[o] + xv4[o + PS4]) + (xv4[o + 2 * PS4] + xv4[o + 3 * PS4]);
        }
        o4[i] = v;
    }
}

// Xc2[nt][256] = Xc[0] + Xc[1]
__global__ __launch_bounds__(256) void reduce_c(
    const float* __restrict__ Xc, float* __restrict__ Xc2)
{
    const size_t PS4 = (size_t)12800 * 64;
    const f32x4* x4 = (const f32x4*)Xc;
    f32x4* o4 = (f32x4*)Xc2;
    const size_t total = (size_t)12800 * 64;
    for (size_t i = (size_t)blockIdx.x * 256 + threadIdx.x; i < total;
         i += (size_t)gridDim.x * 256) {
        o4[i] = x4[i] + x4[i + PS4];
    }
}

// ---------------- Loihi scans: 3-buffer block pipeline (depth 32) ----------
__device__ __forceinline__ float loihi_step(float xt, float& u, float& v)
{
    u = truncf(u * 0.75f) + 64.f * xt;
    v = truncf(v * 0.96875f) + u;
    if (v >= 5120.f) { v = 0.f; return 1.f; }
    return 0.f;
}

// scan_ab: Xall[nt][1024] (single stream) -> Sc [nt][1024] bf16 (delayed)
__global__ __launch_bounds__(64) void scan_ab(const float* __restrict__ Xall,
                                              u16* __restrict__ Sc)
{
    const int gid = blockIdx.x * 64 + threadIdx.x;   // 32*1024 threads
    const int n = gid >> 10;
    const int c = gid & 1023;
    const float* xr = Xall + (size_t)(n * 400) * 1024 + c;
    u16* srow = Sc + (size_t)(n * 400) * 1024 + c;
    srow[0] = 0;

    float cur[16], nx1[16], nx2[16];
    #pragma unroll
    for (int d = 0; d < 16; ++d) cur[d] = xr[(size_t)d * 1024];
    #pragma unroll
    for (int d = 0; d < 16; ++d) nx1[d] = xr[(size_t)(16 + d) * 1024];

    float u = 0.f, v = 0.f;
    for (int blk = 0; blk < 25; ++blk) {
        const int tb = blk * 16;
        #pragma unroll
        for (int d = 0; d < 16; ++d) {
            const int tl = tb + 32 + d;
            nx2[d] = (tl < 400) ? xr[(size_t)tl * 1024] : 0.f;
        }
        #pragma unroll
        for (int d = 0; d < 16; ++d) {
            const int t = tb + d;
            const float sp = loihi_step(cur[d], u, v);
            if (t < 399) srow[(size_t)(t + 1) * 1024] = (sp != 0.f) ? (u16)0x3F80 : (u16)0;
        }
        #pragma unroll
        for (int d = 0; d < 16; ++d) { cur[d] = nx1[d]; nx1[d] = nx2[d]; }
    }
}

// scan_c: Xc2[nt][256] (single stream) -> out [n][c][t]
__global__ __launch_bounds__(64) void scan_c(const float* __restrict__ Xc2,
                                             float* __restrict__ out)
{
    const int gid = blockIdx.x * 64 + threadIdx.x;   // 32*256 threads
    const int n = gid >> 8;
    const int c = gid & 255;
    const float* xr = Xc2 + (size_t)(n * 400) * 256 + c;
    float* orow = out + ((size_t)n * 256 + c) * 400;
    orow[0] = 0.f;

    float cur[16], nx1[16], nx2[16];
    #pragma unroll
    for (int d = 0; d < 16; ++d) cur[d] = xr[(size_t)d * 256];
    #pragma unroll
    for (int d = 0; d < 16; ++d) nx1[d] = xr[(size_t)(16 + d) * 256];

    float u = 0.f, v = 0.f;
    for (int blk = 0; blk < 25; ++blk) {
        const int tb = blk * 16;
        #pragma unroll
        for (int d = 0; d < 16; ++d) {
            const int tl = tb + 32 + d;
            nx2[d] = (tl < 400) ? xr[(size_t)tl * 256] : 0.f;
        }
        #pragma unroll
        for (int d = 0; d < 16; ++d) {
            const int t = tb + d;
            const float sp = loihi_step(cur[d], u, v);
            if (t < 399) orow[t + 1] = sp;
        }
        #pragma unroll
        for (int d = 0; d < 16; ++d) { cur[d] = nx1[d]; nx1[d] = nx2[d]; }
    }
}

extern "C" void kernel_launch(void* const* d_in, const int* in_sizes, int n_in,
                              void* d_out, int out_size, void* d_ws, size_t ws_size,
                              hipStream_t stream)
{
    const float* tact   = (const float*)d_in[0];  // [32][156][400]
    const float* vis    = (const float*)d_in[1];  // [32][6300][400]
    const float* W_tact = (const float*)d_in[2];  // [512][156]
    const float* W_vis  = (const float*)d_in[3];  // [512][6300]
    const float* W_comb = (const float*)d_in[4];  // [256][1024]
    float* out = (float*)d_out;                   // [32][256][400]

    const int NT = 32 * 400;            // 12800
    const int Ktp = 256;                // tact K pad: 4 K-tiles of 64
    const int Kvp = 6400;               // vis K pad: 100 K-tiles
    const int Kc  = 1024;               // combi K: 16 K-tiles

    // ---- workspace carve-up: ~316 MB (ws ~1.29 GB per poison-fill) ----
    char* p = (char*)d_ws;
    u16* Sv  = (u16*)p;                p += (size_t)NT * Kvp * 2;        // 163.8MB
    u16* St  = (u16*)p;                p += (size_t)NT * Ktp * 2;        //   6.6MB
    u16* Wt2 = (u16*)p;                p += (size_t)1024 * Ktp * 2;      //   0.5MB
    u16* Wv2 = (u16*)p;                p += (size_t)1024 * Kvp * 2;      //  13.1MB
    u16* Wc2 = (u16*)p;                p += (size_t)512 * Kc * 2;        //   1.0MB
    float* Xv = (float*)p;             p += (size_t)4 * NT * 512 * 4;    // 104.9MB
    float* Xt = (float*)p;             p += (size_t)NT * 512 * 4;        //  26.2MB
    // aliases into Sv region (Sv dead after gemm_l1):
    float* Xall = (float*)Sv;                                      // [NT][1024] f32 52.4MB
    u16*   Sc   = (u16*)((char*)Sv + (size_t)NT * 1024 * 4);       // [NT][1024] bf16 26.2MB
    float* Xc   = (float*)((char*)Sv + (size_t)NT * 1024 * 6);     // [2][NT][256] f32 26.2MB
    float* Xc2  = (float*)((char*)Sv + (size_t)NT * 1024 * 6 + (size_t)NT * 1024 * 2); // 13.1MB

    // 1) fused prep: all W splits + both spike transposes
    prep<<<dim3(24320), 256, 0, stream>>>(vis, tact, W_vis, W_tact, W_comb,
                                          Sv, St, Wv2, Wt2, Wc2);

    // 2) fused layer-1 GEMM: vis (z=4 co-located) + tact
    gemm_l1<<<dim3(4, 50, 5), 512, 0, stream>>>(Wv2, Sv, Xv, Wt2, St, Xt);

    // 3) fold partials -> Xall, then scan layers 1+2 -> combi spikes
    reduce_ab<<<dim3(2048), 256, 0, stream>>>(Xt, Xv, Xall);
    scan_ab<<<dim3((32 * 1024) / 64), 64, 0, stream>>>(Xall, Sc);

    // 4) combi GEMM (z=2 chunks of 8 K-tiles) -> fold -> scan -> out
    gemm_g<<<dim3(2, 50, 2), 512, 0, stream>>>(Wc2, Sc, Xc, 512, Kc, 8);
    reduce_c<<<dim3(1024), 256, 0, stream>>>(Xc, Xc2);
    scan_c<<<dim3((32 * 256) / 64), 64, 0, stream>>>(Xc2, out);

    (void)in_sizes; (void)n_in; (void)out_size; (void)ws_size;
}

// Round 14
// 366.312 us; speedup vs baseline: 1.8739x; 1.0849x over previous
//
#include <hip/hip_runtime.h>

// Loihi SNN, 3 layers of (GEMM -> Loihi scan -> delay).
// Round 14: recombine r11's best GEMM with r13's best aux.
//  - vis K-split back to z=2 (r11 co-location map; z=4 cost +21us in
//    write traffic + prologue overhead).
//  - reduce kernels FUSED into scans: block-pipelined (8-step blocks,
//    3 buffers, separate per-stream arrays so sums happen at consume
//    time -> loads stay in flight; 32 outstanding <= 63 vmcnt cap).
//    Deletes Xall/Xc2 round-trips (-144 MB traffic, -2 launches).
//  - prep, gemm_g, gemm core: unchanged from round 13.

typedef unsigned short u16;
typedef unsigned int u32;
typedef __attribute__((ext_vector_type(8))) short short8;
typedef __attribute__((ext_vector_type(4))) float f32x4;

#define GLOAD16(g, l)                                                         \
    __builtin_amdgcn_global_load_lds(                                         \
        (const __attribute__((address_space(1))) u32*)(g),                    \
        (__attribute__((address_space(3))) u32*)(l), 16, 0, 0)

__device__ __forceinline__ u16 f2bf_trunc(float x) {
    return (u16)(__float_as_uint(x) >> 16);
}

// ---------------- fused prep: W splits + spike transposes ----------------
__device__ __forceinline__ void cvt_body(const float* __restrict__ S,
                                         u16* __restrict__ Sp,
                                         int I, int KLD, int n, int i0, int t0,
                                         u16 (*tile)[88])
{
    const int tid = threadIdx.x;
    const int il = tid >> 2;
    const int q  = tid & 3;
    const int gi = i0 + il;
    const bool iok = gi < I;
    const float* srow = S + ((size_t)n * I + gi) * 400 + t0;

    #pragma unroll
    for (int s = 0; s < 4; ++s) {
        const int fi = s * 4 + q;
        const int tl = fi * 4;
        float4 v = make_float4(0.f, 0.f, 0.f, 0.f);
        if (iok && (t0 + tl) < 400)
            v = *(const float4*)(srow + tl);
        tile[tl + 0][il] = f2bf_trunc(v.x);
        tile[tl + 1][il] = f2bf_trunc(v.y);
        tile[tl + 2][il] = f2bf_trunc(v.z);
        tile[tl + 3][il] = f2bf_trunc(v.w);
    }
    __syncthreads();

    const int tl = tid >> 2;
    const int iq = tid & 3;
    const int t  = t0 + tl;
    const int go = i0 + iq * 16;
    if (t < 400 && go < KLD) {
        u16* dst = Sp + (size_t)(n * 400 + t) * KLD + go;
        *(short8*)(dst)     = *(const short8*)&tile[tl][iq * 16];
        *(short8*)(dst + 8) = *(const short8*)&tile[tl][iq * 16 + 8];
    }
}

__device__ __forceinline__ void split_one(const float* __restrict__ W,
                                          u16* __restrict__ W2,
                                          int C, int K, int KLD, int idx)
{
    const int c = idx / KLD;
    const int k = idx - c * KLD;
    float w = (k < K) ? W[(size_t)c * K + k] : 0.f;
    u32 b  = __float_as_uint(w);
    u32 hb = (b + 0x7FFFu + ((b >> 16) & 1u)) & 0xFFFF0000u;
    float r = w - __uint_as_float(hb);
    u32 rb = __float_as_uint(r);
    u32 mb = (rb + 0x7FFFu + ((rb >> 16) & 1u)) & 0xFFFF0000u;
    const int rh = ((c >> 4) << 5) | (c & 15);
    W2[(size_t)rh * KLD + k]        = (u16)(hb >> 16);
    W2[(size_t)(rh + 16) * KLD + k] = (u16)(mb >> 16);
}

// grid: [0,22400) vis cvt | [22400,23296) tact cvt | [23296,24320) splits
__global__ __launch_bounds__(256) void prep(
    const float* __restrict__ vis, const float* __restrict__ tact,
    const float* __restrict__ Wv, const float* __restrict__ Wt,
    const float* __restrict__ Wc,
    u16* __restrict__ Sv, u16* __restrict__ St,
    u16* __restrict__ Wv2, u16* __restrict__ Wt2, u16* __restrict__ Wc2)
{
    __shared__ u16 tile[64][88];
    const int b = blockIdx.x;
    if (b < 22400) {
        const int x = b % 7, y = (b / 7) % 100, n = b / 700;
        cvt_body(vis, Sv, 6300, 6400, n, y * 64, x * 64, tile);
    } else if (b < 23296) {
        const int b2 = b - 22400;
        const int x = b2 % 7, y = (b2 / 7) % 4, n = b2 / 28;
        cvt_body(tact, St, 156, 256, n, y * 64, x * 64, tile);
    } else {
        const int b3 = b - 23296;   // 0..1023
        for (int e = b3 * 256 + (int)threadIdx.x; e < 3670016; e += 1024 * 256) {
            if (e < 3276800)        split_one(Wv, Wv2, 512, 6300, 6400, e);
            else if (e < 3407872)   split_one(Wt, Wt2, 512, 156,  256,  e - 3276800);
            else                    split_one(Wc, Wc2, 256, 1024, 1024, e - 3407872);
        }
    }
}

// ---------------- 8-phase GEMM core (fold-epilogue) ----------------
__device__ __forceinline__ void gemm_core(
    const u16* __restrict__ A, const u16* __restrict__ B,
    float* __restrict__ X, int M2, int KLD, int kt0, int nk,
    int bx, int by, u16* lds)
{
    const int c0  = bx * 256;
    const int nt0 = by * 256;
    const int tid  = threadIdx.x;
    const int lane = tid & 63, w = tid >> 6;
    const int wm = w >> 2, wn = w & 3;
    const int l15 = lane & 15, l16 = lane >> 4;

    const int swzg  = (l16 ^ ((l15 >> 1) & 3)) * 8;
    const int aBase = (wm * 128 + l15) * 32 + swzg;          // + mf*512
    const int bBase = 16384 + (wn * 64 + l15) * 32 + swzg;   // + nf*512

    const int gsw = ((tid & 3) ^ ((tid >> 3) & 3)) * 8;
    const u16* pA = A + (size_t)(c0 + (tid >> 2)) * KLD + gsw;
    const u16* pB = B + (size_t)(nt0 + (tid >> 2)) * KLD + gsw;
    u16* const ldsW = &lds[w * 512];

#define STG(op, d, ks, tt) do {                                               \
    const u16* s_ = ((op) ? pB : pA) + (size_t)(tt) * 64 + (ks) * 32;         \
    GLOAD16(s_, ldsW + (d) * 32768 + (op) * 16384 + (ks) * 8192);             \
    GLOAD16(s_ + (size_t)128 * KLD,                                           \
            ldsW + (d) * 32768 + (op) * 16384 + (ks) * 8192 + 4096);          \
} while (0)

#define PH(d, ks, mh, LOADB, STAGE_STMT, WAIT_STMT) do {                      \
    short8 a_[4];                                                             \
    _Pragma("unroll")                                                         \
    for (int mf = 0; mf < 4; ++mf)                                            \
        a_[mf] = *(const short8*)&lds[(d) * 32768 + (ks) * 8192 + aBase       \
                                      + ((mh) * 4 + mf) * 512];               \
    if (LOADB) {                                                              \
        _Pragma("unroll")                                                     \
        for (int nf = 0; nf < 4; ++nf)                                        \
            bcur[nf] = *(const short8*)&lds[(d) * 32768 + (ks) * 8192 + bBase \
                                            + nf * 512];                      \
    }                                                                         \
    STAGE_STMT;                                                               \
    __builtin_amdgcn_s_barrier();                                             \
    asm volatile("s_waitcnt lgkmcnt(0)" ::: "memory");                        \
    __builtin_amdgcn_sched_barrier(0);                                        \
    __builtin_amdgcn_s_setprio(1);                                            \
    _Pragma("unroll")                                                         \
    for (int mf = 0; mf < 4; ++mf)                                            \
        _Pragma("unroll")                                                     \
        for (int nf = 0; nf < 4; ++nf)                                        \
            acc[(mh) * 4 + mf][nf] = __builtin_amdgcn_mfma_f32_16x16x32_bf16( \
                a_[mf], bcur[nf], acc[(mh) * 4 + mf][nf], 0, 0, 0);           \
    __builtin_amdgcn_s_setprio(0);                                            \
    WAIT_STMT;                                                                \
    __builtin_amdgcn_s_barrier();                                             \
    asm volatile("" ::: "memory");                                            \
} while (0)

    f32x4 acc[8][4];
    #pragma unroll
    for (int i = 0; i < 8; ++i)
        #pragma unroll
        for (int j = 0; j < 4; ++j)
            acc[i][j] = (f32x4){0.f, 0.f, 0.f, 0.f};

    // prologue: tile0 all 4 units (d0), tile1 A-ks0/B-ks0/B-ks1 (d1)
    STG(0, 0, 0, kt0); STG(1, 0, 0, kt0); STG(0, 0, 1, kt0); STG(1, 0, 1, kt0);
    STG(0, 1, 0, kt0 + 1); STG(1, 1, 0, kt0 + 1); STG(1, 1, 1, kt0 + 1);
    asm volatile("s_waitcnt vmcnt(0)" ::: "memory");
    __builtin_amdgcn_s_barrier();
    asm volatile("" ::: "memory");

    const int I = nk >> 1;
    for (int i = 0; i < I; ++i) {
        const int t = kt0 + 2 * i;
        const bool pf = (i < I - 1);
        short8 bcur[4];
        // tile t (dbuf 0)
        PH(0, 0, 0, 1, { STG(0, 1, 1, t + 1); }, );
        PH(0, 0, 1, 0, { if (pf) STG(1, 0, 0, t + 2); }, );
        PH(0, 1, 0, 1, { if (pf) STG(0, 0, 0, t + 2); }, );
        PH(0, 1, 1, 0, { if (pf) STG(1, 0, 1, t + 2); },
           { if (pf) asm volatile("s_waitcnt vmcnt(6)" ::: "memory");
             else    asm volatile("s_waitcnt vmcnt(0)" ::: "memory"); });
        // tile t+1 (dbuf 1)
        PH(1, 0, 0, 1, { if (pf) STG(0, 0, 1, t + 2); }, );
        PH(1, 0, 1, 0, { if (pf) STG(1, 1, 0, t + 3); }, );
        PH(1, 1, 0, 1, { if (pf) STG(0, 1, 0, t + 3); }, );
        PH(1, 1, 1, 0, { if (pf) STG(1, 1, 1, t + 3); },
           { if (pf) asm volatile("s_waitcnt vmcnt(6)" ::: "memory");
             else    asm volatile("s_waitcnt vmcnt(0)" ::: "memory"); });
    }

    // fold-epilogue: channel col = bx*128 + wm*64 + j*16 + l16*4
    const int Mout = M2 >> 1;
    #pragma unroll
    for (int j = 0; j < 4; ++j) {
        const int cg = bx * 128 + wm * 64 + j * 16 + l16 * 4;
        #pragma unroll
        for (int nf = 0; nf < 4; ++nf) {
            const int nt = nt0 + wn * 64 + nf * 16 + l15;
            f32x4 s = acc[2 * j][nf] + acc[2 * j + 1][nf];
            *(f32x4*)&X[(size_t)nt * Mout + cg] = s;
        }
    }
#undef STG
#undef PH
}

// layer-1 fused: f<400 -> vis (z=2 K-chunks, co-located), else tact.
__global__ __launch_bounds__(512, 2) void gemm_l1(
    const u16* __restrict__ Av, const u16* __restrict__ Bv, float* __restrict__ Xv,
    const u16* __restrict__ At, const u16* __restrict__ Bt, float* __restrict__ Xt)
{
    __shared__ u16 lds[65536];
    const int f = blockIdx.x + 4 * (blockIdx.y + 50 * blockIdx.z); // grid (4,50,3)
    if (f < 400) {
        // co-location: panel (by,bz) mates bx=0..3 at f = 16m+2p+{0,1,8,9}
        const int p   = (f & 7) >> 1;              // XCD-pair 0..3
        const int k   = ((f >> 3) << 1) | (f & 1); // 0..99
        const int bx  = k & 3;
        const int pi  = 25 * p + (k >> 2);         // 0..99
        const int by  = pi % 50;
        const int bz  = pi / 50;
        gemm_core(Av, Bv, Xv + (size_t)bz * 12800 * 512, 1024, 6400,
                  bz * 50, 50, bx, by, lds);
    } else {
        const int f2 = f - 400;                    // 0..199
        gemm_core(At, Bt, Xt, 1024, 256, 0, 4, f2 & 3, f2 >> 2, lds);
    }
}

// generic (combi): simple bijective XCD swizzle.
__global__ __launch_bounds__(512, 2) void gemm_g(
    const u16* __restrict__ A, const u16* __restrict__ B,
    float* __restrict__ Xbase, int M2, int KLD, int ktPerZ)
{
    __shared__ u16 lds[65536];
    const int Dx = gridDim.x, Dy = gridDim.y;
    int f = blockIdx.x + Dx * (blockIdx.y + Dy * blockIdx.z);
    const int nwg = Dx * Dy * gridDim.z;
    f = (f & 7) * (nwg >> 3) + (f >> 3);
    const int bx = f % Dx;
    const int by = (f / Dx) % Dy;
    const int bz = f / (Dx * Dy);
    gemm_core(A, B, Xbase + (size_t)bz * 12800 * (M2 >> 1), M2, KLD,
              bz * ktPerZ, ktPerZ, bx, by, lds);
}

// ------- Loihi scans: fused partial-sum + 3-buffer block pipeline -------
__device__ __forceinline__ float loihi_step(float xt, float& u, float& v)
{
    u = truncf(u * 0.75f) + 64.f * xt;
    v = truncf(v * 0.96875f) + u;
    if (v >= 5120.f) { v = 0.f; return 1.f; }
    return 0.f;
}

// scan_ab: tact Xt[nt][512] + vis Xv[2][nt][512] -> Sc [nt][1024] bf16
// block pipeline: 8-step blocks, 3 buffers, per-stream arrays (sums at
// consume time so loads stay outstanding; 32 loads in flight max).
__global__ __launch_bounds__(64) void scan_ab(const float* __restrict__ Xt,
                                              const float* __restrict__ Xv,
                                              u16* __restrict__ Sc)
{
    const int gid = blockIdx.x * 64 + threadIdx.x;   // 32*1024 threads
    const int n = gid >> 10;
    const int c = gid & 1023;
    const size_t PS = (size_t)12800 * 512;
    const bool isv = (c >= 512);                     // wave-uniform (512%64==0)
    const float* xr = isv ? (Xv + (size_t)(n * 400) * 512 + (c - 512))
                          : (Xt + (size_t)(n * 400) * 512 + c);
    u16* srow = Sc + (size_t)(n * 400) * 1024 + c;
    srow[0] = 0;

    float a0[8], b0[8], a1[8], b1[8], a2[8], b2[8];
    #pragma unroll
    for (int d = 0; d < 8; ++d) {
        a0[d] = xr[(size_t)d * 512];
        b0[d] = isv ? xr[(size_t)d * 512 + PS] : 0.f;
    }
    #pragma unroll
    for (int d = 0; d < 8; ++d) {
        a1[d] = xr[(size_t)(8 + d) * 512];
        b1[d] = isv ? xr[(size_t)(8 + d) * 512 + PS] : 0.f;
    }

    float u = 0.f, v = 0.f;
    for (int blk = 0; blk < 50; ++blk) {
        const int tb = blk * 8;
        #pragma unroll
        for (int d = 0; d < 8; ++d) {
            const int tl = tb + 16 + d;
            a2[d] = (tl < 400) ? xr[(size_t)tl * 512] : 0.f;
            b2[d] = (isv && tl < 400) ? xr[(size_t)tl * 512 + PS] : 0.f;
        }
        #pragma unroll
        for (int d = 0; d < 8; ++d) {
            const int t = tb + d;
            const float sp = loihi_step(a0[d] + b0[d], u, v);
            if (t < 399) srow[(size_t)(t + 1) * 1024] = (sp != 0.f) ? (u16)0x3F80 : (u16)0;
        }
        #pragma unroll
        for (int d = 0; d < 8; ++d) {
            a0[d] = a1[d]; b0[d] = b1[d];
            a1[d] = a2[d]; b1[d] = b2[d];
        }
    }
}

// scan_c: combi Xc[2][nt][256] -> out [n][c][t]
__global__ __launch_bounds__(64) void scan_c(const float* __restrict__ Xc,
                                             float* __restrict__ out)
{
    const int gid = blockIdx.x * 64 + threadIdx.x;   // 32*256 threads
    const int n = gid >> 8;
    const int c = gid & 255;
    const size_t PS = (size_t)12800 * 256;
    const float* xr = Xc + (size_t)(n * 400) * 256 + c;
    float* orow = out + ((size_t)n * 256 + c) * 400;
    orow[0] = 0.f;

    float a0[8], b0[8], a1[8], b1[8], a2[8], b2[8];
    #pragma unroll
    for (int d = 0; d < 8; ++d) {
        a0[d] = xr[(size_t)d * 256];
        b0[d] = xr[(size_t)d * 256 + PS];
    }
    #pragma unroll
    for (int d = 0; d < 8; ++d) {
        a1[d] = xr[(size_t)(8 + d) * 256];
        b1[d] = xr[(size_t)(8 + d) * 256 + PS];
    }

    float u = 0.f, v = 0.f;
    for (int blk = 0; blk < 50; ++blk) {
        const int tb = blk * 8;
        #pragma unroll
        for (int d = 0; d < 8; ++d) {
            const int tl = tb + 16 + d;
            a2[d] = (tl < 400) ? xr[(size_t)tl * 256] : 0.f;
            b2[d] = (tl < 400) ? xr[(size_t)tl * 256 + PS] : 0.f;
        }
        #pragma unroll
        for (int d = 0; d < 8; ++d) {
            const int t = tb + d;
            const float sp = loihi_step(a0[d] + b0[d], u, v);
            if (t < 399) orow[t + 1] = sp;
        }
        #pragma unroll
        for (int d = 0; d < 8; ++d) {
            a0[d] = a1[d]; b0[d] = b1[d];
            a1[d] = a2[d]; b1[d] = b2[d];
        }
    }
}

extern "C" void kernel_launch(void* const* d_in, const int* in_sizes, int n_in,
                              void* d_out, int out_size, void* d_ws, size_t ws_size,
                              hipStream_t stream)
{
    const float* tact   = (const float*)d_in[0];  // [32][156][400]
    const float* vis    = (const float*)d_in[1];  // [32][6300][400]
    const float* W_tact = (const float*)d_in[2];  // [512][156]
    const float* W_vis  = (const float*)d_in[3];  // [512][6300]
    const float* W_comb = (const float*)d_in[4];  // [256][1024]
    float* out = (float*)d_out;                   // [32][256][400]

    const int NT = 32 * 400;            // 12800
    const int Ktp = 256;                // tact K pad: 4 K-tiles of 64
    const int Kvp = 6400;               // vis K pad: 100 K-tiles
    const int Kc  = 1024;               // combi K: 16 K-tiles

    // ---- workspace carve-up: ~264 MB ----
    char* p = (char*)d_ws;
    u16* Sv  = (u16*)p;                p += (size_t)NT * Kvp * 2;        // 163.8MB
    u16* St  = (u16*)p;                p += (size_t)NT * Ktp * 2;        //   6.6MB
    u16* Wt2 = (u16*)p;                p += (size_t)1024 * Ktp * 2;      //   0.5MB
    u16* Wv2 = (u16*)p;                p += (size_t)1024 * Kvp * 2;      //  13.1MB
    u16* Wc2 = (u16*)p;                p += (size_t)512 * Kc * 2;        //   1.0MB
    float* Xv = (float*)p;             p += (size_t)2 * NT * 512 * 4;    //  52.4MB
    float* Xt = (float*)p;             p += (size_t)NT * 512 * 4;        //  26.2MB
    // aliases into Sv region (Sv dead after gemm_l1):
    u16*   Sc = (u16*)Sv;                                          // [NT][1024] bf16
    float* Xc = (float*)((char*)Sv + (size_t)NT * 1024 * 2);       // [2][NT][256] f32

    // 1) fused prep: all W splits + both spike transposes
    prep<<<dim3(24320), 256, 0, stream>>>(vis, tact, W_vis, W_tact, W_comb,
                                          Sv, St, Wv2, Wt2, Wc2);

    // 2) fused layer-1 GEMM: vis (z=2 co-located) + tact
    gemm_l1<<<dim3(4, 50, 3), 512, 0, stream>>>(Wv2, Sv, Xv, Wt2, St, Xt);

    // 3) fused scan layers 1+2 (sums 2 vis partials inline) -> combi spikes
    scan_ab<<<dim3((32 * 1024) / 64), 64, 0, stream>>>(Xt, Xv, Sc);

    // 4) combi GEMM (z=2 chunks of 8 K-tiles) -> fused scan -> out
    gemm_g<<<dim3(2, 50, 2), 512, 0, stream>>>(Wc2, Sc, Xc, 512, Kc, 8);
    scan_c<<<dim3((32 * 256) / 64), 64, 0, stream>>>(Xc, out);

    (void)in_sizes; (void)n_in; (void)out_size; (void)ws_size;
}

// Round 15
// 354.905 us; speedup vs baseline: 1.9342x; 1.0321x over previous
//
#include <hip/hip_runtime.h>

// Loihi SNN, 3 layers of (GEMM -> Loihi scan -> delay).
// Round 15:
//  - vis GEMM z=1: 200 blocks x 100 K-tiles -> ONE block-wave makespan
//    (~172us floor) instead of 2.34 waves; 56 leftover CUs absorb the 200
//    short tact blocks. Single vis partial (exact k-ascending sum chain).
//    Co-location: panel by mates at f = 16m+2j+{0,1,8,9} -> one XCD pair
//    (bijective, incl. tail f=192..199).
//  - prep vis-cvt widened: 64t x 256i per block (4 sub-tiles), output rows
//    written 512B-contiguous; LDS tile[64][268] (write banks {0,8,16,24}
//    octets -> 2-way; reads short4-pair, 8B aligned).
//  - scan_ab: single stream per channel (tact | vis), 3x8 block pipeline.
//  - gemm core / gemm_g / scan_c / splits unchanged from round 14.

typedef unsigned short u16;
typedef unsigned int u32;
typedef __attribute__((ext_vector_type(4))) short short4v;
typedef __attribute__((ext_vector_type(8))) short short8;
typedef __attribute__((ext_vector_type(4))) float f32x4;

#define GLOAD16(g, l)                                                         \
    __builtin_amdgcn_global_load_lds(                                         \
        (const __attribute__((address_space(1))) u32*)(g),                    \
        (__attribute__((address_space(3))) u32*)(l), 16, 0, 0)

__device__ __forceinline__ u16 f2bf_trunc(float x) {
    return (u16)(__float_as_uint(x) >> 16);
}

// ---------------- prep: W splits + spike transposes ----------------
// wide vis transpose: [t0,t0+64) x [i0,i0+256) of batch n
__device__ __forceinline__ void cvt_wide(const float* __restrict__ S,
                                         u16* __restrict__ Sp,
                                         int I, int KLD, int n, int i0, int t0,
                                         u16 (*tile)[268])
{
    const int tid = threadIdx.x;
    const int il = tid >> 2;       // 0..63 i within sub-tile
    const int q  = tid & 3;

    #pragma unroll
    for (int ii = 0; ii < 4; ++ii) {
        const int gi = i0 + ii * 64 + il;
        const bool iok = gi < I;
        const float* srow = S + ((size_t)n * I + gi) * 400 + t0;
        #pragma unroll
        for (int s = 0; s < 4; ++s) {
            const int tl = (s * 4 + q) * 4;
            float4 v = make_float4(0.f, 0.f, 0.f, 0.f);
            if (iok && (t0 + tl) < 400)
                v = *(const float4*)(srow + tl);
            tile[tl + 0][ii * 64 + il] = f2bf_trunc(v.x);
            tile[tl + 1][ii * 64 + il] = f2bf_trunc(v.y);
            tile[tl + 2][ii * 64 + il] = f2bf_trunc(v.z);
            tile[tl + 3][ii * 64 + il] = f2bf_trunc(v.w);
        }
    }
    __syncthreads();

    const int row = tid >> 3;      // 0..31
    const int lc  = tid & 7;
    #pragma unroll
    for (int h = 0; h < 2; ++h) {
        const int tl = h * 32 + row;
        const int t = t0 + tl;
        if (t < 400) {
            u16* dst = Sp + (size_t)(n * 400 + t) * KLD + i0;
            #pragma unroll
            for (int w = 0; w < 4; ++w) {
                const int io = w * 64 + lc * 8;
                *(short4v*)(dst + io)     = *(const short4v*)&tile[tl][io];
                *(short4v*)(dst + io + 4) = *(const short4v*)&tile[tl][io + 4];
            }
        }
    }
    __syncthreads();
}

// narrow transpose (tact): 64t x 64i
__device__ __forceinline__ void cvt_body(const float* __restrict__ S,
                                         u16* __restrict__ Sp,
                                         int I, int KLD, int n, int i0, int t0,
                                         u16 (*tile)[88])
{
    const int tid = threadIdx.x;
    const int il = tid >> 2;
    const int q  = tid & 3;
    const int gi = i0 + il;
    const bool iok = gi < I;
    const float* srow = S + ((size_t)n * I + gi) * 400 + t0;

    #pragma unroll
    for (int s = 0; s < 4; ++s) {
        const int tl = (s * 4 + q) * 4;
        float4 v = make_float4(0.f, 0.f, 0.f, 0.f);
        if (iok && (t0 + tl) < 400)
            v = *(const float4*)(srow + tl);
        tile[tl + 0][il] = f2bf_trunc(v.x);
        tile[tl + 1][il] = f2bf_trunc(v.y);
        tile[tl + 2][il] = f2bf_trunc(v.z);
        tile[tl + 3][il] = f2bf_trunc(v.w);
    }
    __syncthreads();

    const int tl = tid >> 2;
    const int iq = tid & 3;
    const int t  = t0 + tl;
    const int go = i0 + iq * 16;
    if (t < 400 && go < KLD) {
        u16* dst = Sp + (size_t)(n * 400 + t) * KLD + go;
        *(short8*)(dst)     = *(const short8*)&tile[tl][iq * 16];
        *(short8*)(dst + 8) = *(const short8*)&tile[tl][iq * 16 + 8];
    }
    __syncthreads();
}

__device__ __forceinline__ void split_one(const float* __restrict__ W,
                                          u16* __restrict__ W2,
                                          int C, int K, int KLD, int idx)
{
    const int c = idx / KLD;
    const int k = idx - c * KLD;
    float w = (k < K) ? W[(size_t)c * K + k] : 0.f;
    u32 b  = __float_as_uint(w);
    u32 hb = (b + 0x7FFFu + ((b >> 16) & 1u)) & 0xFFFF0000u;
    float r = w - __uint_as_float(hb);
    u32 rb = __float_as_uint(r);
    u32 mb = (rb + 0x7FFFu + ((rb >> 16) & 1u)) & 0xFFFF0000u;
    const int rh = ((c >> 4) << 5) | (c & 15);
    W2[(size_t)rh * KLD + k]        = (u16)(hb >> 16);
    W2[(size_t)(rh + 16) * KLD + k] = (u16)(mb >> 16);
}

// grid: [0,5600) vis wide-cvt | [5600,6496) tact cvt | [6496,7520) splits
__global__ __launch_bounds__(256) void prep(
    const float* __restrict__ vis, const float* __restrict__ tact,
    const float* __restrict__ Wv, const float* __restrict__ Wt,
    const float* __restrict__ Wc,
    u16* __restrict__ Sv, u16* __restrict__ St,
    u16* __restrict__ Wv2, u16* __restrict__ Wt2, u16* __restrict__ Wc2)
{
    __shared__ u16 tile[64][268];   // 34.3 KB
    const int b = blockIdx.x;
    if (b < 5600) {
        const int x = b % 7, y = (b / 7) % 25, n = b / 175;
        cvt_wide(vis, Sv, 6300, 6400, n, y * 256, x * 64, tile);
    } else if (b < 6496) {
        const int b2 = b - 5600;
        const int x = b2 % 7, y = (b2 / 7) % 4, n = b2 / 28;
        cvt_body(tact, St, 156, 256, n, y * 64, x * 64, (u16(*)[88])tile);
    } else {
        const int b3 = b - 6496;   // 0..1023
        for (int e = b3 * 256 + (int)threadIdx.x; e < 3670016; e += 1024 * 256) {
            if (e < 3276800)        split_one(Wv, Wv2, 512, 6300, 6400, e);
            else if (e < 3407872)   split_one(Wt, Wt2, 512, 156,  256,  e - 3276800);
            else                    split_one(Wc, Wc2, 256, 1024, 1024, e - 3407872);
        }
    }
}

// ---------------- 8-phase GEMM core (fold-epilogue) ----------------
__device__ __forceinline__ void gemm_core(
    const u16* __restrict__ A, const u16* __restrict__ B,
    float* __restrict__ X, int M2, int KLD, int kt0, int nk,
    int bx, int by, u16* lds)
{
    const int c0  = bx * 256;
    const int nt0 = by * 256;
    const int tid  = threadIdx.x;
    const int lane = tid & 63, w = tid >> 6;
    const int wm = w >> 2, wn = w & 3;
    const int l15 = lane & 15, l16 = lane >> 4;

    const int swzg  = (l16 ^ ((l15 >> 1) & 3)) * 8;
    const int aBase = (wm * 128 + l15) * 32 + swzg;          // + mf*512
    const int bBase = 16384 + (wn * 64 + l15) * 32 + swzg;   // + nf*512

    const int gsw = ((tid & 3) ^ ((tid >> 3) & 3)) * 8;
    const u16* pA = A + (size_t)(c0 + (tid >> 2)) * KLD + gsw;
    const u16* pB = B + (size_t)(nt0 + (tid >> 2)) * KLD + gsw;
    u16* const ldsW = &lds[w * 512];

#define STG(op, d, ks, tt) do {                                               \
    const u16* s_ = ((op) ? pB : pA) + (size_t)(tt) * 64 + (ks) * 32;         \
    GLOAD16(s_, ldsW + (d) * 32768 + (op) * 16384 + (ks) * 8192);             \
    GLOAD16(s_ + (size_t)128 * KLD,                                           \
            ldsW + (d) * 32768 + (op) * 16384 + (ks) * 8192 + 4096);          \
} while (0)

#define PH(d, ks, mh, LOADB, STAGE_STMT, WAIT_STMT) do {                      \
    short8 a_[4];                                                             \
    _Pragma("unroll")                                                         \
    for (int mf = 0; mf < 4; ++mf)                                            \
        a_[mf] = *(const short8*)&lds[(d) * 32768 + (ks) * 8192 + aBase       \
                                      + ((mh) * 4 + mf) * 512];               \
    if (LOADB) {                                                              \
        _Pragma("unroll")                                                     \
        for (int nf = 0; nf < 4; ++nf)                                        \
            bcur[nf] = *(const short8*)&lds[(d) * 32768 + (ks) * 8192 + bBase \
                                            + nf * 512];                      \
    }                                                                         \
    STAGE_STMT;                                                               \
    __builtin_amdgcn_s_barrier();                                             \
    asm volatile("s_waitcnt lgkmcnt(0)" ::: "memory");                        \
    __builtin_amdgcn_sched_barrier(0);                                        \
    __builtin_amdgcn_s_setprio(1);                                            \
    _Pragma("unroll")                                                         \
    for (int mf = 0; mf < 4; ++mf)                                            \
        _Pragma("unroll")                                                     \
        for (int nf = 0; nf < 4; ++nf)                                        \
            acc[(mh) * 4 + mf][nf] = __builtin_amdgcn_mfma_f32_16x16x32_bf16( \
                a_[mf], bcur[nf], acc[(mh) * 4 + mf][nf], 0, 0, 0);           \
    __builtin_amdgcn_s_setprio(0);                                            \
    WAIT_STMT;                                                                \
    __builtin_amdgcn_s_barrier();                                             \
    asm volatile("" ::: "memory");                                            \
} while (0)

    f32x4 acc[8][4];
    #pragma unroll
    for (int i = 0; i < 8; ++i)
        #pragma unroll
        for (int j = 0; j < 4; ++j)
            acc[i][j] = (f32x4){0.f, 0.f, 0.f, 0.f};

    // prologue: tile0 all 4 units (d0), tile1 A-ks0/B-ks0/B-ks1 (d1)
    STG(0, 0, 0, kt0); STG(1, 0, 0, kt0); STG(0, 0, 1, kt0); STG(1, 0, 1, kt0);
    STG(0, 1, 0, kt0 + 1); STG(1, 1, 0, kt0 + 1); STG(1, 1, 1, kt0 + 1);
    asm volatile("s_waitcnt vmcnt(0)" ::: "memory");
    __builtin_amdgcn_s_barrier();
    asm volatile("" ::: "memory");

    const int I = nk >> 1;
    for (int i = 0; i < I; ++i) {
        const int t = kt0 + 2 * i;
        const bool pf = (i < I - 1);
        short8 bcur[4];
        // tile t (dbuf 0)
        PH(0, 0, 0, 1, { STG(0, 1, 1, t + 1); }, );
        PH(0, 0, 1, 0, { if (pf) STG(1, 0, 0, t + 2); }, );
        PH(0, 1, 0, 1, { if (pf) STG(0, 0, 0, t + 2); }, );
        PH(0, 1, 1, 0, { if (pf) STG(1, 0, 1, t + 2); },
           { if (pf) asm volatile("s_waitcnt vmcnt(6)" ::: "memory");
             else    asm volatile("s_waitcnt vmcnt(0)" ::: "memory"); });
        // tile t+1 (dbuf 1)
        PH(1, 0, 0, 1, { if (pf) STG(0, 0, 1, t + 2); }, );
        PH(1, 0, 1, 0, { if (pf) STG(1, 1, 0, t + 3); }, );
        PH(1, 1, 0, 1, { if (pf) STG(0, 1, 0, t + 3); }, );
        PH(1, 1, 1, 0, { if (pf) STG(1, 1, 1, t + 3); },
           { if (pf) asm volatile("s_waitcnt vmcnt(6)" ::: "memory");
             else    asm volatile("s_waitcnt vmcnt(0)" ::: "memory"); });
    }

    // fold-epilogue: channel col = bx*128 + wm*64 + j*16 + l16*4
    const int Mout = M2 >> 1;
    #pragma unroll
    for (int j = 0; j < 4; ++j) {
        const int cg = bx * 128 + wm * 64 + j * 16 + l16 * 4;
        #pragma unroll
        for (int nf = 0; nf < 4; ++nf) {
            const int nt = nt0 + wn * 64 + nf * 16 + l15;
            f32x4 s = acc[2 * j][nf] + acc[2 * j + 1][nf];
            *(f32x4*)&X[(size_t)nt * Mout + cg] = s;
        }
    }
#undef STG
#undef PH
}

// layer-1 fused: f<200 -> vis (z=1, full K, co-located pairs), else tact.
__global__ __launch_bounds__(512, 2) void gemm_l1(
    const u16* __restrict__ Av, const u16* __restrict__ Bv, float* __restrict__ Xv,
    const u16* __restrict__ At, const u16* __restrict__ Bt, float* __restrict__ Xt)
{
    __shared__ u16 lds[65536];
    const int f = blockIdx.x + 4 * (blockIdx.y + 50 * blockIdx.z); // grid (4,50,2)
    if (f < 200) {
        int bx, by;
        if (f < 192) {
            // mates of panel by at f = 16m + 2j + {0,1,8,9}  -> XCD pair j
            const int m = f >> 4, r = f & 15;
            by = m * 4 + ((r & 7) >> 1);
            bx = ((r >> 3) << 1) | (r & 1);
        } else {
            const int k = f - 192;
            by = 48 + (k >> 2);
            bx = k & 3;
        }
        gemm_core(Av, Bv, Xv, 1024, 6400, 0, 100, bx, by, lds);
    } else {
        const int f2 = f - 200;                    // 0..199
        gemm_core(At, Bt, Xt, 1024, 256, 0, 4, f2 & 3, f2 >> 2, lds);
    }
}

// generic (combi): simple bijective XCD swizzle.
__global__ __launch_bounds__(512, 2) void gemm_g(
    const u16* __restrict__ A, const u16* __restrict__ B,
    float* __restrict__ Xbase, int M2, int KLD, int ktPerZ)
{
    __shared__ u16 lds[65536];
    const int Dx = gridDim.x, Dy = gridDim.y;
    int f = blockIdx.x + Dx * (blockIdx.y + Dy * blockIdx.z);
    const int nwg = Dx * Dy * gridDim.z;
    f = (f & 7) * (nwg >> 3) + (f >> 3);
    const int bx = f % Dx;
    const int by = (f / Dx) % Dy;
    const int bz = f / (Dx * Dy);
    gemm_core(A, B, Xbase + (size_t)bz * 12800 * (M2 >> 1), M2, KLD,
              bz * ktPerZ, ktPerZ, bx, by, lds);
}

// ------- Loihi scans: 3x8 block pipeline -------
__device__ __forceinline__ float loihi_step(float xt, float& u, float& v)
{
    u = truncf(u * 0.75f) + 64.f * xt;
    v = truncf(v * 0.96875f) + u;
    if (v >= 5120.f) { v = 0.f; return 1.f; }
    return 0.f;
}

// scan_ab: tact Xt[nt][512] + vis Xv[nt][512] (single partials) -> Sc bf16
__global__ __launch_bounds__(64) void scan_ab(const float* __restrict__ Xt,
                                              const float* __restrict__ Xv,
                                              u16* __restrict__ Sc)
{
    const int gid = blockIdx.x * 64 + threadIdx.x;   // 32*1024 threads
    const int n = gid >> 10;
    const int c = gid & 1023;
    const float* xr = (c < 512)
        ? Xt + (size_t)(n * 400) * 512 + c
        : Xv + (size_t)(n * 400) * 512 + (c - 512);
    u16* srow = Sc + (size_t)(n * 400) * 1024 + c;
    srow[0] = 0;

    float c0[8], c1[8], c2[8];
    #pragma unroll
    for (int d = 0; d < 8; ++d) c0[d] = xr[(size_t)d * 512];
    #pragma unroll
    for (int d = 0; d < 8; ++d) c1[d] = xr[(size_t)(8 + d) * 512];

    float u = 0.f, v = 0.f;
    for (int blk = 0; blk < 50; ++blk) {
        const int tb = blk * 8;
        #pragma unroll
        for (int d = 0; d < 8; ++d) {
            const int tl = tb + 16 + d;
            c2[d] = (tl < 400) ? xr[(size_t)tl * 512] : 0.f;
        }
        #pragma unroll
        for (int d = 0; d < 8; ++d) {
            const int t = tb + d;
            const float sp = loihi_step(c0[d], u, v);
            if (t < 399) srow[(size_t)(t + 1) * 1024] = (sp != 0.f) ? (u16)0x3F80 : (u16)0;
        }
        #pragma unroll
        for (int d = 0; d < 8; ++d) { c0[d] = c1[d]; c1[d] = c2[d]; }
    }
}

// scan_c: combi Xc[2][nt][256] -> out [n][c][t]
__global__ __launch_bounds__(64) void scan_c(const float* __restrict__ Xc,
                                             float* __restrict__ out)
{
    const int gid = blockIdx.x * 64 + threadIdx.x;   // 32*256 threads
    const int n = gid >> 8;
    const int c = gid & 255;
    const size_t PS = (size_t)12800 * 256;
    const float* xr = Xc + (size_t)(n * 400) * 256 + c;
    float* orow = out + ((size_t)n * 256 + c) * 400;
    orow[0] = 0.f;

    float a0[8], b0[8], a1[8], b1[8], a2[8], b2[8];
    #pragma unroll
    for (int d = 0; d < 8; ++d) {
        a0[d] = xr[(size_t)d * 256];
        b0[d] = xr[(size_t)d * 256 + PS];
    }
    #pragma unroll
    for (int d = 0; d < 8; ++d) {
        a1[d] = xr[(size_t)(8 + d) * 256];
        b1[d] = xr[(size_t)(8 + d) * 256 + PS];
    }

    float u = 0.f, v = 0.f;
    for (int blk = 0; blk < 50; ++blk) {
        const int tb = blk * 8;
        #pragma unroll
        for (int d = 0; d < 8; ++d) {
            const int tl = tb + 16 + d;
            a2[d] = (tl < 400) ? xr[(size_t)tl * 256] : 0.f;
            b2[d] = (tl < 400) ? xr[(size_t)tl * 256 + PS] : 0.f;
        }
        #pragma unroll
        for (int d = 0; d < 8; ++d) {
            const int t = tb + d;
            const float sp = loihi_step(a0[d] + b0[d], u, v);
            if (t < 399) orow[t + 1] = sp;
        }
        #pragma unroll
        for (int d = 0; d < 8; ++d) {
            a0[d] = a1[d]; b0[d] = b1[d];
            a1[d] = a2[d]; b1[d] = b2[d];
        }
    }
}

extern "C" void kernel_launch(void* const* d_in, const int* in_sizes, int n_in,
                              void* d_out, int out_size, void* d_ws, size_t ws_size,
                              hipStream_t stream)
{
    const float* tact   = (const float*)d_in[0];  // [32][156][400]
    const float* vis    = (const float*)d_in[1];  // [32][6300][400]
    const float* W_tact = (const float*)d_in[2];  // [512][156]
    const float* W_vis  = (const float*)d_in[3];  // [512][6300]
    const float* W_comb = (const float*)d_in[4];  // [256][1024]
    float* out = (float*)d_out;                   // [32][256][400]

    const int NT = 32 * 400;            // 12800
    const int Ktp = 256;                // tact K pad: 4 K-tiles of 64
    const int Kvp = 6400;               // vis K pad: 100 K-tiles
    const int Kc  = 1024;               // combi K: 16 K-tiles

    // ---- workspace carve-up: ~238 MB ----
    char* p = (char*)d_ws;
    u16* Sv  = (u16*)p;                p += (size_t)NT * Kvp * 2;        // 163.8MB
    u16* St  = (u16*)p;                p += (size_t)NT * Ktp * 2;        //   6.6MB
    u16* Wt2 = (u16*)p;                p += (size_t)1024 * Ktp * 2;      //   0.5MB
    u16* Wv2 = (u16*)p;                p += (size_t)1024 * Kvp * 2;      //  13.1MB
    u16* Wc2 = (u16*)p;                p += (size_t)512 * Kc * 2;        //   1.0MB
    float* Xv = (float*)p;             p += (size_t)NT * 512 * 4;        //  26.2MB
    float* Xt = (float*)p;             p += (size_t)NT * 512 * 4;        //  26.2MB
    // aliases into Sv region (Sv dead after gemm_l1):
    u16*   Sc = (u16*)Sv;                                          // [NT][1024] bf16
    float* Xc = (float*)((char*)Sv + (size_t)NT * 1024 * 2);       // [2][NT][256] f32

    // 1) fused prep: all W splits + both spike transposes
    prep<<<dim3(7520), 256, 0, stream>>>(vis, tact, W_vis, W_tact, W_comb,
                                         Sv, St, Wv2, Wt2, Wc2);

    // 2) fused layer-1 GEMM: vis (z=1, co-located) + tact
    gemm_l1<<<dim3(4, 50, 2), 512, 0, stream>>>(Wv2, Sv, Xv, Wt2, St, Xt);

    // 3) scan layers 1+2 (single streams) -> combi spikes
    scan_ab<<<dim3((32 * 1024) / 64), 64, 0, stream>>>(Xt, Xv, Sc);

    // 4) combi GEMM (z=2 chunks of 8 K-tiles) -> fused scan -> out
    gemm_g<<<dim3(2, 50, 2), 512, 0, stream>>>(Wc2, Sc, Xc, 512, Kc, 8);
    scan_c<<<dim3((32 * 256) / 64), 64, 0, stream>>>(Xc, out);

    (void)in_sizes; (void)n_in; (void)out_size; (void)ws_size;
}

// Round 16
// 342.575 us; speedup vs baseline: 2.0038x; 1.0360x over previous
//
#include <hip/hip_runtime.h>

// Loihi SNN, 3 layers of (GEMM -> Loihi scan -> delay).
// Round 16: register-prefetch GEMM schedule.
//   Each phase: [bcur reads | aN prefetch(p+1) | MFMA(aC) | barrier | stage |
//   counted vmcnt]. One barrier/phase (8/iter, was 16); NO lgkmcnt(0) drains
//   (compiler emits counted lgkm for deps; prefetch stays in flight under
//   MFMA). Stage plan shifted +1 phase (ph1:B1(t+1) ... ph8:A0(t+3));
//   vmcnt(6) at odd-phase ends (vmcnt(0) in final iter). Full hazard table
//   re-derived: every stage target's last-read completes >=1 barrier before
//   overwrite; every stage->first-read has >=3 stage-units (6 loads) slack.
//   Everything else (prep/scans/maps/layouts) identical to round 15.

typedef unsigned short u16;
typedef unsigned int u32;
typedef __attribute__((ext_vector_type(4))) short short4v;
typedef __attribute__((ext_vector_type(8))) short short8;
typedef __attribute__((ext_vector_type(4))) float f32x4;

#define GLOAD16(g, l)                                                         \
    __builtin_amdgcn_global_load_lds(                                         \
        (const __attribute__((address_space(1))) u32*)(g),                    \
        (__attribute__((address_space(3))) u32*)(l), 16, 0, 0)

__device__ __forceinline__ u16 f2bf_trunc(float x) {
    return (u16)(__float_as_uint(x) >> 16);
}

// ---------------- prep: W splits + spike transposes ----------------
__device__ __forceinline__ void cvt_wide(const float* __restrict__ S,
                                         u16* __restrict__ Sp,
                                         int I, int KLD, int n, int i0, int t0,
                                         u16 (*tile)[268])
{
    const int tid = threadIdx.x;
    const int il = tid >> 2;
    const int q  = tid & 3;

    #pragma unroll
    for (int ii = 0; ii < 4; ++ii) {
        const int gi = i0 + ii * 64 + il;
        const bool iok = gi < I;
        const float* srow = S + ((size_t)n * I + gi) * 400 + t0;
        #pragma unroll
        for (int s = 0; s < 4; ++s) {
            const int tl = (s * 4 + q) * 4;
            float4 v = make_float4(0.f, 0.f, 0.f, 0.f);
            if (iok && (t0 + tl) < 400)
                v = *(const float4*)(srow + tl);
            tile[tl + 0][ii * 64 + il] = f2bf_trunc(v.x);
            tile[tl + 1][ii * 64 + il] = f2bf_trunc(v.y);
            tile[tl + 2][ii * 64 + il] = f2bf_trunc(v.z);
            tile[tl + 3][ii * 64 + il] = f2bf_trunc(v.w);
        }
    }
    __syncthreads();

    const int row = tid >> 3;
    const int lc  = tid & 7;
    #pragma unroll
    for (int h = 0; h < 2; ++h) {
        const int tl = h * 32 + row;
        const int t = t0 + tl;
        if (t < 400) {
            u16* dst = Sp + (size_t)(n * 400 + t) * KLD + i0;
            #pragma unroll
            for (int w = 0; w < 4; ++w) {
                const int io = w * 64 + lc * 8;
                *(short4v*)(dst + io)     = *(const short4v*)&tile[tl][io];
                *(short4v*)(dst + io + 4) = *(const short4v*)&tile[tl][io + 4];
            }
        }
    }
    __syncthreads();
}

__device__ __forceinline__ void cvt_body(const float* __restrict__ S,
                                         u16* __restrict__ Sp,
                                         int I, int KLD, int n, int i0, int t0,
                                         u16 (*tile)[88])
{
    const int tid = threadIdx.x;
    const int il = tid >> 2;
    const int q  = tid & 3;
    const int gi = i0 + il;
    const bool iok = gi < I;
    const float* srow = S + ((size_t)n * I + gi) * 400 + t0;

    #pragma unroll
    for (int s = 0; s < 4; ++s) {
        const int tl = (s * 4 + q) * 4;
        float4 v = make_float4(0.f, 0.f, 0.f, 0.f);
        if (iok && (t0 + tl) < 400)
            v = *(const float4*)(srow + tl);
        tile[tl + 0][il] = f2bf_trunc(v.x);
        tile[tl + 1][il] = f2bf_trunc(v.y);
        tile[tl + 2][il] = f2bf_trunc(v.z);
        tile[tl + 3][il] = f2bf_trunc(v.w);
    }
    __syncthreads();

    const int tl = tid >> 2;
    const int iq = tid & 3;
    const int t  = t0 + tl;
    const int go = i0 + iq * 16;
    if (t < 400 && go < KLD) {
        u16* dst = Sp + (size_t)(n * 400 + t) * KLD + go;
        *(short8*)(dst)     = *(const short8*)&tile[tl][iq * 16];
        *(short8*)(dst + 8) = *(const short8*)&tile[tl][iq * 16 + 8];
    }
    __syncthreads();
}

__device__ __forceinline__ void split_one(const float* __restrict__ W,
                                          u16* __restrict__ W2,
                                          int C, int K, int KLD, int idx)
{
    const int c = idx / KLD;
    const int k = idx - c * KLD;
    float w = (k < K) ? W[(size_t)c * K + k] : 0.f;
    u32 b  = __float_as_uint(w);
    u32 hb = (b + 0x7FFFu + ((b >> 16) & 1u)) & 0xFFFF0000u;
    float r = w - __uint_as_float(hb);
    u32 rb = __float_as_uint(r);
    u32 mb = (rb + 0x7FFFu + ((rb >> 16) & 1u)) & 0xFFFF0000u;
    const int rh = ((c >> 4) << 5) | (c & 15);
    W2[(size_t)rh * KLD + k]        = (u16)(hb >> 16);
    W2[(size_t)(rh + 16) * KLD + k] = (u16)(mb >> 16);
}

// grid: [0,5600) vis wide-cvt | [5600,6496) tact cvt | [6496,7520) splits
__global__ __launch_bounds__(256) void prep(
    const float* __restrict__ vis, const float* __restrict__ tact,
    const float* __restrict__ Wv, const float* __restrict__ Wt,
    const float* __restrict__ Wc,
    u16* __restrict__ Sv, u16* __restrict__ St,
    u16* __restrict__ Wv2, u16* __restrict__ Wt2, u16* __restrict__ Wc2)
{
    __shared__ u16 tile[64][268];
    const int b = blockIdx.x;
    if (b < 5600) {
        const int x = b % 7, y = (b / 7) % 25, n = b / 175;
        cvt_wide(vis, Sv, 6300, 6400, n, y * 256, x * 64, tile);
    } else if (b < 6496) {
        const int b2 = b - 5600;
        const int x = b2 % 7, y = (b2 / 7) % 4, n = b2 / 28;
        cvt_body(tact, St, 156, 256, n, y * 64, x * 64, (u16(*)[88])tile);
    } else {
        const int b3 = b - 6496;
        for (int e = b3 * 256 + (int)threadIdx.x; e < 3670016; e += 1024 * 256) {
            if (e < 3276800)        split_one(Wv, Wv2, 512, 6300, 6400, e);
            else if (e < 3407872)   split_one(Wt, Wt2, 512, 156,  256,  e - 3276800);
            else                    split_one(Wc, Wc2, 256, 1024, 1024, e - 3407872);
        }
    }
}

// ------------ register-prefetch 8-phase GEMM core (fold-epilogue) ----------
__device__ __forceinline__ void gemm_core(
    const u16* __restrict__ A, const u16* __restrict__ B,
    float* __restrict__ X, int M2, int KLD, int kt0, int nk,
    int bx, int by, u16* lds)
{
    const int c0  = bx * 256;
    const int nt0 = by * 256;
    const int tid  = threadIdx.x;
    const int lane = tid & 63, w = tid >> 6;
    const int wm = w >> 2, wn = w & 3;
    const int l15 = lane & 15, l16 = lane >> 4;

    const int swzg  = (l16 ^ ((l15 >> 1) & 3)) * 8;
    const int aBase = (wm * 128 + l15) * 32 + swzg;          // + mf*512
    const int bBase = 16384 + (wn * 64 + l15) * 32 + swzg;   // + nf*512

    const int gsw = ((tid & 3) ^ ((tid >> 3) & 3)) * 8;
    const u16* pA = A + (size_t)(c0 + (tid >> 2)) * KLD + gsw;
    const u16* pB = B + (size_t)(nt0 + (tid >> 2)) * KLD + gsw;
    u16* const ldsW = &lds[w * 512];

#define STG(op, d, ks, tt) do {                                               \
    const u16* s_ = ((op) ? pB : pA) + (size_t)(tt) * 64 + (ks) * 32;         \
    GLOAD16(s_, ldsW + (d) * 32768 + (op) * 16384 + (ks) * 8192);             \
    GLOAD16(s_ + (size_t)128 * KLD,                                           \
            ldsW + (d) * 32768 + (op) * 16384 + (ks) * 8192 + 4096);          \
} while (0)

// phase: bcur (opt) | aN prefetch (p+1) | MFMA(aC) | barrier | stage | wait
#define PH(d, ks, mh, LOADB, dn, ksn, mhn, AIN, AOUT, STAGE_STMT, WAIT_STMT)  \
do {                                                                          \
    if (LOADB) {                                                              \
        _Pragma("unroll")                                                     \
        for (int nf = 0; nf < 4; ++nf)                                        \
            bcur[nf] = *(const short8*)&lds[(d) * 32768 + (ks) * 8192 + bBase \
                                            + nf * 512];                      \
    }                                                                         \
    _Pragma("unroll")                                                         \
    for (int mf = 0; mf < 4; ++mf)                                            \
        AOUT[mf] = *(const short8*)&lds[(dn) * 32768 + (ksn) * 8192 + aBase   \
                                        + ((mhn) * 4 + mf) * 512];            \
    __builtin_amdgcn_sched_barrier(0);                                        \
    __builtin_amdgcn_s_setprio(1);                                            \
    _Pragma("unroll")                                                         \
    for (int mf = 0; mf < 4; ++mf)                                            \
        _Pragma("unroll")                                                     \
        for (int nf = 0; nf < 4; ++nf)                                        \
            acc[(mh) * 4 + mf][nf] = __builtin_amdgcn_mfma_f32_16x16x32_bf16( \
                AIN[mf], bcur[nf], acc[(mh) * 4 + mf][nf], 0, 0, 0);          \
    __builtin_amdgcn_s_setprio(0);                                            \
    __builtin_amdgcn_s_barrier();                                             \
    asm volatile("" ::: "memory");                                            \
    STAGE_STMT;                                                               \
    WAIT_STMT;                                                                \
    asm volatile("" ::: "memory");                                            \
} while (0)

#define VM6 asm volatile("s_waitcnt vmcnt(6)" ::: "memory")
#define VM0 asm volatile("s_waitcnt vmcnt(0)" ::: "memory")

    f32x4 acc[8][4];
    #pragma unroll
    for (int i = 0; i < 8; ++i)
        #pragma unroll
        for (int j = 0; j < 4; ++j)
            acc[i][j] = (f32x4){0.f, 0.f, 0.f, 0.f};

    // prologue: 6 units — tile0 all 4, tile1 A-ks0/B-ks0.
    STG(0, 0, 0, kt0); STG(1, 0, 0, kt0); STG(0, 0, 1, kt0); STG(1, 0, 1, kt0);
    STG(0, 1, 0, kt0 + 1); STG(1, 1, 0, kt0 + 1);
    VM0;
    __builtin_amdgcn_s_barrier();
    asm volatile("" ::: "memory");

    short8 aX[4], aY[4], bcur[4];
    #pragma unroll
    for (int mf = 0; mf < 4; ++mf)
        aX[mf] = *(const short8*)&lds[aBase + mf * 512];   // (d0,ks0,mh0)

    const int I = nk >> 1;
    for (int i = 0; i < I; ++i) {
        const int t = kt0 + 2 * i;
        const bool pf = (i < I - 1);
        // tile t (d0)
        PH(0, 0, 0, 1, 0, 0, 1, aX, aY, { STG(1, 1, 1, t + 1); },
           { if (pf) VM6; else VM0; });
        PH(0, 0, 1, 0, 0, 1, 0, aY, aX, { STG(0, 1, 1, t + 1); }, );
        PH(0, 1, 0, 1, 0, 1, 1, aX, aY, { if (pf) STG(1, 0, 0, t + 2); },
           { if (pf) VM6; else VM0; });
        PH(0, 1, 1, 0, 1, 0, 0, aY, aX, { if (pf) STG(0, 0, 0, t + 2); }, );
        // tile t+1 (d1)
        PH(1, 0, 0, 1, 1, 0, 1, aX, aY, { if (pf) STG(1, 0, 1, t + 2); },
           { if (pf) VM6; else VM0; });
        PH(1, 0, 1, 0, 1, 1, 0, aY, aX, { if (pf) STG(0, 0, 1, t + 2); }, );
        PH(1, 1, 0, 1, 1, 1, 1, aX, aY, { if (pf) STG(1, 1, 0, t + 3); },
           { if (pf) VM6; else VM0; });
        PH(1, 1, 1, 0, 0, 0, 0, aY, aX, { if (pf) STG(0, 1, 0, t + 3); }, );
    }

    // fold-epilogue: channel col = bx*128 + wm*64 + j*16 + l16*4
    const int Mout = M2 >> 1;
    #pragma unroll
    for (int j = 0; j < 4; ++j) {
        const int cg = bx * 128 + wm * 64 + j * 16 + l16 * 4;
        #pragma unroll
        for (int nf = 0; nf < 4; ++nf) {
            const int nt = nt0 + wn * 64 + nf * 16 + l15;
            f32x4 s = acc[2 * j][nf] + acc[2 * j + 1][nf];
            *(f32x4*)&X[(size_t)nt * Mout + cg] = s;
        }
    }
#undef STG
#undef PH
#undef VM6
#undef VM0
}

// layer-1 fused: f<200 -> vis (z=1, full K, co-located pairs), else tact.
__global__ __launch_bounds__(512, 2) void gemm_l1(
    const u16* __restrict__ Av, const u16* __restrict__ Bv, float* __restrict__ Xv,
    const u16* __restrict__ At, const u16* __restrict__ Bt, float* __restrict__ Xt)
{
    __shared__ u16 lds[65536];
    const int f = blockIdx.x + 4 * (blockIdx.y + 50 * blockIdx.z); // grid (4,50,2)
    if (f < 200) {
        int bx, by;
        if (f < 192) {
            const int m = f >> 4, r = f & 15;
            by = m * 4 + ((r & 7) >> 1);
            bx = ((r >> 3) << 1) | (r & 1);
        } else {
            const int k = f - 192;
            by = 48 + (k >> 2);
            bx = k & 3;
        }
        gemm_core(Av, Bv, Xv, 1024, 6400, 0, 100, bx, by, lds);
    } else {
        const int f2 = f - 200;
        gemm_core(At, Bt, Xt, 1024, 256, 0, 4, f2 & 3, f2 >> 2, lds);
    }
}

// generic (combi): simple bijective XCD swizzle.
__global__ __launch_bounds__(512, 2) void gemm_g(
    const u16* __restrict__ A, const u16* __restrict__ B,
    float* __restrict__ Xbase, int M2, int KLD, int ktPerZ)
{
    __shared__ u16 lds[65536];
    const int Dx = gridDim.x, Dy = gridDim.y;
    int f = blockIdx.x + Dx * (blockIdx.y + Dy * blockIdx.z);
    const int nwg = Dx * Dy * gridDim.z;
    f = (f & 7) * (nwg >> 3) + (f >> 3);
    const int bx = f % Dx;
    const int by = (f / Dx) % Dy;
    const int bz = f / (Dx * Dy);
    gemm_core(A, B, Xbase + (size_t)bz * 12800 * (M2 >> 1), M2, KLD,
              bz * ktPerZ, ktPerZ, bx, by, lds);
}

// ------- Loihi scans: 3x8 block pipeline -------
__device__ __forceinline__ float loihi_step(float xt, float& u, float& v)
{
    u = truncf(u * 0.75f) + 64.f * xt;
    v = truncf(v * 0.96875f) + u;
    if (v >= 5120.f) { v = 0.f; return 1.f; }
    return 0.f;
}

// scan_ab: tact Xt[nt][512] + vis Xv[nt][512] (single partials) -> Sc bf16
__global__ __launch_bounds__(64) void scan_ab(const float* __restrict__ Xt,
                                              const float* __restrict__ Xv,
                                              u16* __restrict__ Sc)
{
    const int gid = blockIdx.x * 64 + threadIdx.x;   // 32*1024 threads
    const int n = gid >> 10;
    const int c = gid & 1023;
    const float* xr = (c < 512)
        ? Xt + (size_t)(n * 400) * 512 + c
        : Xv + (size_t)(n * 400) * 512 + (c - 512);
    u16* srow = Sc + (size_t)(n * 400) * 1024 + c;
    srow[0] = 0;

    float c0[8], c1[8], c2[8];
    #pragma unroll
    for (int d = 0; d < 8; ++d) c0[d] = xr[(size_t)d * 512];
    #pragma unroll
    for (int d = 0; d < 8; ++d) c1[d] = xr[(size_t)(8 + d) * 512];

    float u = 0.f, v = 0.f;
    for (int blk = 0; blk < 50; ++blk) {
        const int tb = blk * 8;
        #pragma unroll
        for (int d = 0; d < 8; ++d) {
            const int tl = tb + 16 + d;
            c2[d] = (tl < 400) ? xr[(size_t)tl * 512] : 0.f;
        }
        #pragma unroll
        for (int d = 0; d < 8; ++d) {
            const int t = tb + d;
            const float sp = loihi_step(c0[d], u, v);
            if (t < 399) srow[(size_t)(t + 1) * 1024] = (sp != 0.f) ? (u16)0x3F80 : (u16)0;
        }
        #pragma unroll
        for (int d = 0; d < 8; ++d) { c0[d] = c1[d]; c1[d] = c2[d]; }
    }
}

// scan_c: combi Xc[2][nt][256] -> out [n][c][t]
__global__ __launch_bounds__(64) void scan_c(const float* __restrict__ Xc,
                                             float* __restrict__ out)
{
    const int gid = blockIdx.x * 64 + threadIdx.x;   // 32*256 threads
    const int n = gid >> 8;
    const int c = gid & 255;
    const size_t PS = (size_t)12800 * 256;
    const float* xr = Xc + (size_t)(n * 400) * 256 + c;
    float* orow = out + ((size_t)n * 256 + c) * 400;
    orow[0] = 0.f;

    float a0[8], b0[8], a1[8], b1[8], a2[8], b2[8];
    #pragma unroll
    for (int d = 0; d < 8; ++d) {
        a0[d] = xr[(size_t)d * 256];
        b0[d] = xr[(size_t)d * 256 + PS];
    }
    #pragma unroll
    for (int d = 0; d < 8; ++d) {
        a1[d] = xr[(size_t)(8 + d) * 256];
        b1[d] = xr[(size_t)(8 + d) * 256 + PS];
    }

    float u = 0.f, v = 0.f;
    for (int blk = 0; blk < 50; ++blk) {
        const int tb = blk * 8;
        #pragma unroll
        for (int d = 0; d < 8; ++d) {
            const int tl = tb + 16 + d;
            a2[d] = (tl < 400) ? xr[(size_t)tl * 256] : 0.f;
            b2[d] = (tl < 400) ? xr[(size_t)tl * 256 + PS] : 0.f;
        }
        #pragma unroll
        for (int d = 0; d < 8; ++d) {
            const int t = tb + d;
            const float sp = loihi_step(a0[d] + b0[d], u, v);
            if (t < 399) orow[t + 1] = sp;
        }
        #pragma unroll
        for (int d = 0; d < 8; ++d) {
            a0[d] = a1[d]; b0[d] = b1[d];
            a1[d] = a2[d]; b1[d] = b2[d];
        }
    }
}

extern "C" void kernel_launch(void* const* d_in, const int* in_sizes, int n_in,
                              void* d_out, int out_size, void* d_ws, size_t ws_size,
                              hipStream_t stream)
{
    const float* tact   = (const float*)d_in[0];  // [32][156][400]
    const float* vis    = (const float*)d_in[1];  // [32][6300][400]
    const float* W_tact = (const float*)d_in[2];  // [512][156]
    const float* W_vis  = (const float*)d_in[3];  // [512][6300]
    const float* W_comb = (const float*)d_in[4];  // [256][1024]
    float* out = (float*)d_out;                   // [32][256][400]

    const int NT = 32 * 400;            // 12800
    const int Ktp = 256;                // tact K pad: 4 K-tiles of 64
    const int Kvp = 6400;               // vis K pad: 100 K-tiles
    const int Kc  = 1024;               // combi K: 16 K-tiles

    // ---- workspace carve-up: ~238 MB ----
    char* p = (char*)d_ws;
    u16* Sv  = (u16*)p;                p += (size_t)NT * Kvp * 2;        // 163.8MB
    u16* St  = (u16*)p;                p += (size_t)NT * Ktp * 2;        //   6.6MB
    u16* Wt2 = (u16*)p;                p += (size_t)1024 * Ktp * 2;      //   0.5MB
    u16* Wv2 = (u16*)p;                p += (size_t)1024 * Kvp * 2;      //  13.1MB
    u16* Wc2 = (u16*)p;                p += (size_t)512 * Kc * 2;        //   1.0MB
    float* Xv = (float*)p;             p += (size_t)NT * 512 * 4;        //  26.2MB
    float* Xt = (float*)p;             p += (size_t)NT * 512 * 4;        //  26.2MB
    // aliases into Sv region (Sv dead after gemm_l1):
    u16*   Sc = (u16*)Sv;                                          // [NT][1024] bf16
    float* Xc = (float*)((char*)Sv + (size_t)NT * 1024 * 2);       // [2][NT][256] f32

    // 1) fused prep: all W splits + both spike transposes
    prep<<<dim3(7520), 256, 0, stream>>>(vis, tact, W_vis, W_tact, W_comb,
                                         Sv, St, Wv2, Wt2, Wc2);

    // 2) fused layer-1 GEMM: vis (z=1, co-located) + tact
    gemm_l1<<<dim3(4, 50, 2), 512, 0, stream>>>(Wv2, Sv, Xv, Wt2, St, Xt);

    // 3) scan layers 1+2 (single streams) -> combi spikes
    scan_ab<<<dim3((32 * 1024) / 64), 64, 0, stream>>>(Xt, Xv, Sc);

    // 4) combi GEMM (z=2 chunks of 8 K-tiles) -> fused scan -> out
    gemm_g<<<dim3(2, 50, 2), 512, 0, stream>>>(Wc2, Sc, Xc, 512, Kc, 8);
    scan_c<<<dim3((32 * 256) / 64), 64, 0, stream>>>(Xc, out);

    (void)in_sizes; (void)n_in; (void)out_size; (void)ws_size;
}